// Round 4
// baseline (1796.994 us; speedup 1.0000x reference)
//
#include <hip/hip_runtime.h>
#include <stdint.h>

// SIREN batched MLP, MI355X/gfx950 — round 3 (resubmit; r3 bench was an infra
// timeout): register-resident activations, half-pass layers (64 feats per
// pass) + pinned waves_per_eu(2,2) to kill the round-2 scratch spills (VGPR
// budget 256, demand ~170).
// Precision (verified r1/r2, absmax 0.0039): L1 split-MFMA, L2/L3 hi/lo split,
// L4 plain f16, L5 plain f16 M-padded.

typedef _Float16 f16x8 __attribute__((ext_vector_type(8)));
typedef float f32x16 __attribute__((ext_vector_type(16)));

#define MFMA __builtin_amdgcn_mfma_f32_32x32x16_f16

#define B_ 32
#define N_ 32768

// flat param offsets (floats)
#define OFF_W1 0
#define OFF_B1 256
#define OFF_W2 384
#define OFF_B2 16768
#define OFF_W3 16896
#define OFF_B3 33280
#define OFF_W4 33408
#define OFF_B4 49792
#define OFF_W5 49920
#define OFF_B5 50304
#define NPARAM 50307

// ws per-batch image offsets (bytes); frag-ordered: [c][mt][lane]*16B
#define O_L1H 0
#define O_L1L 4096
#define O_L2H 8192
#define O_W2L 40960
#define O_L3H 73728
#define O_L4H 106496
#define O_L5H 139264
#define LDSSET 147456          /* bytes staged to LDS */
#define O_W3L 147456           /* streamed from global (L2-resident) */
#define SWS   180224           /* per-batch ws stride */

__device__ __forceinline__ float fast_sin30(float v) {
    float t = v * 4.77464829275686f;   // 30 / (2*pi)
    t = t - floorf(t);
    return __builtin_amdgcn_sinf(t);
}

__device__ __forceinline__ uint32_t pack2(_Float16 a, _Float16 b) {
    union { _Float16 h[2]; uint32_t u; } x;
    x.h[0] = a; x.h[1] = b;
    return x.u;
}

// ---------------------------------------------------------------------------
// Prep: split params into f16 hi/lo, A-frag-ordered images (layout verified
// end-to-end in r1/r2).
// A-frag for 32x32x16_f16: lane l holds A[m = 32*mt + (l&31)][k = 16c + 8*(l>>5) + e].
// ---------------------------------------------------------------------------
__global__ __launch_bounds__(64) void siren_prep(const float* __restrict__ p0,
                                                 char* __restrict__ ws) {
    const int u = blockIdx.x;      // 0..107 image unit
    const int b = blockIdx.y;
    const int lane = threadIdx.x;
    const int jn = lane & 31;
    const int h = lane >> 5;
    const float* p = p0 + (size_t)b * NPARAM;
    char* wb = ws + (size_t)b * SWS;

    float v[8];
    size_t hoff = 0, loff = 0;
    bool haslo = false;

    if (u < 4) {                               // L1: [mt][lane], k=0:Wx 1:Wy 2:bias
        int mt = u, j = mt * 32 + jn;
#pragma unroll
        for (int e = 0; e < 8; ++e) {
            int k = h * 8 + e;
            v[e] = (k == 0) ? p[OFF_W1 + j * 2]
                 : (k == 1) ? p[OFF_W1 + j * 2 + 1]
                 : (k == 2) ? p[OFF_B1 + j] : 0.f;
        }
        hoff = O_L1H + (size_t)(mt * 64 + lane) * 16;
        loff = O_L1L + (size_t)(mt * 64 + lane) * 16;
        haslo = true;
    } else if (u < 100) {                      // L2/L3/L4: [c][mt][lane]
        int vv = u - 4;
        int layer = vv >> 5;                   // 0,1,2
        int r = vv & 31;
        int c = r >> 2, mt = r & 3;
        int j = mt * 32 + jn, kb = c * 16 + h * 8;
        int wOff = (layer == 0) ? OFF_W2 : (layer == 1) ? OFF_W3 : OFF_W4;
#pragma unroll
        for (int e = 0; e < 8; ++e) v[e] = p[wOff + j * 128 + kb + e];
        size_t idx = (size_t)((c * 4 + mt) * 64 + lane) * 16;
        if (layer == 0)      { hoff = O_L2H + idx; loff = O_W2L + idx; haslo = true; }
        else if (layer == 1) { hoff = O_L3H + idx; loff = O_W3L + idx; haslo = true; }
        else                 { hoff = O_L4H + idx; haslo = false; }
    } else {                                   // L5: [c][lane], rows 3..31 zero
        int c = u - 100, j = jn, kb = c * 16 + h * 8;
#pragma unroll
        for (int e = 0; e < 8; ++e) v[e] = (j < 3) ? p[OFF_W5 + j * 128 + kb + e] : 0.f;
        hoff = O_L5H + (size_t)(c * 64 + lane) * 16;
        haslo = false;
    }

    f16x8 hv, lv;
#pragma unroll
    for (int e = 0; e < 8; ++e) {
        _Float16 hh = (_Float16)v[e];
        hv[e] = hh;
        lv[e] = (_Float16)(v[e] - (float)hh);
    }
    *(f16x8*)(wb + hoff) = hv;
    if (haslo) *(f16x8*)(wb + loff) = lv;
}

// ---------------------------------------------------------------------------
// Main kernel: 512 threads = 8 waves = 2 waves/SIMD (1 block/CU, LDS-bound).
// Wave processes 32 points/iter, 16 iters. Layers run as two 64-feat halves.
// ---------------------------------------------------------------------------
__global__ __launch_bounds__(512)
__attribute__((amdgpu_waves_per_eu(2, 2)))
void siren_main(const float* __restrict__ xg,
                const float* __restrict__ pg,
                float* __restrict__ out,
                const char* __restrict__ ws) {
    extern __shared__ __align__(16) char smem[];
    __shared__ float sBias[3][128];

    const int t = threadIdx.x;
    const int b = blockIdx.x;
    const int grp = blockIdx.y;
    const char* wb = ws + (size_t)b * SWS;
    const float* p = pg + (size_t)b * NPARAM;

    // stage weight images to LDS: 147456 B = 9216 float4 = 512 thr * 18
    {
        const float4* src = (const float4*)wb;
        float4* dst = (float4*)smem;
#pragma unroll
        for (int i = 0; i < 18; ++i) dst[t + i * 512] = src[t + i * 512];
    }
    if (t < 384) {
        int li = t >> 7, f = t & 127;
        sBias[li][f] = p[(li == 0 ? OFF_B2 : li == 1 ? OFF_B3 : OFF_B4) + f];
    }
    const float b5_0 = p[OFF_B5], b5_1 = p[OFF_B5 + 1], b5_2 = p[OFF_B5 + 2];
    __syncthreads();

    const int lane = t & 63;
    const int wv = t >> 6;
    const int n = lane & 31;
    const int h = lane >> 5;
    const int lb = lane * 16;

    union UF { f16x8 v; uint32_t w[4]; };

    // bias init for one half: acc a[mt2], feat(reg r) = 32(2half+mt2)+ (r&3)+8(r>>2)+4h
    auto init_bias_half = [&](f32x16 (&ac)[2], int li, int half) {
#pragma unroll
        for (int mt2 = 0; mt2 < 2; ++mt2) {
            int mt = half * 2 + mt2;
#pragma unroll
            for (int rg = 0; rg < 4; ++rg) {
                float4 bb = *(const float4*)&sBias[li][mt * 32 + rg * 8 + h * 4];
                ac[mt2][rg * 4 + 0] = bb.x; ac[mt2][rg * 4 + 1] = bb.y;
                ac[mt2][rg * 4 + 2] = bb.z; ac[mt2][rg * 4 + 3] = bb.w;
            }
        }
    };

    // epilogue for one half: produces B-frag chunks 4*half .. 4*half+3.
    // (relayout logic verified in r1/r2: low-half lanes keep elems 0-3, swap 4-7.)
    auto epi_split_half = [&](f32x16 (&ac)[2], UF (&Xh)[8], UF (&Xl)[8], int half) {
#pragma unroll
        for (int cc = 0; cc < 4; ++cc) {
            const int c = half * 4 + cc;
            const int mt2 = cc >> 1, g0 = (cc & 1) * 8;
            _Float16 hh[8]; float lo[8];
#pragma unroll
            for (int i = 0; i < 8; ++i) {
                float s = fast_sin30(ac[mt2][g0 + i]);
                hh[i] = (_Float16)s;
                lo[i] = s - (float)hh[i];
            }
            uint32_t hw0 = pack2(hh[0], hh[1]), hw1 = pack2(hh[2], hh[3]);
            uint32_t hw2 = pack2(hh[4], hh[5]), hw3 = pack2(hh[6], hh[7]);
            _Float16 ll[8];
#pragma unroll
            for (int i = 0; i < 8; ++i) ll[i] = (_Float16)lo[i];
            uint32_t lw0 = pack2(ll[0], ll[1]), lw1 = pack2(ll[2], ll[3]);
            uint32_t lw2 = pack2(ll[4], ll[5]), lw3 = pack2(ll[6], ll[7]);

            uint32_t rA = (uint32_t)__shfl_xor((int)(h ? hw0 : hw2), 32);
            uint32_t rB = (uint32_t)__shfl_xor((int)(h ? hw1 : hw3), 32);
            Xh[c].w[0] = h ? rA : hw0;  Xh[c].w[1] = h ? rB : hw1;
            Xh[c].w[2] = h ? hw2 : rA;  Xh[c].w[3] = h ? hw3 : rB;

            uint32_t sA = (uint32_t)__shfl_xor((int)(h ? lw0 : lw2), 32);
            uint32_t sB = (uint32_t)__shfl_xor((int)(h ? lw1 : lw3), 32);
            Xl[c].w[0] = h ? sA : lw0;  Xl[c].w[1] = h ? sB : lw1;
            Xl[c].w[2] = h ? lw2 : sA;  Xl[c].w[3] = h ? lw3 : sB;
        }
    };

    auto epi_hi_half = [&](f32x16 (&ac)[2], UF (&Xh)[8], int half) {
#pragma unroll
        for (int cc = 0; cc < 4; ++cc) {
            const int c = half * 4 + cc;
            const int mt2 = cc >> 1, g0 = (cc & 1) * 8;
            _Float16 hh[8];
#pragma unroll
            for (int i = 0; i < 8; ++i) hh[i] = (_Float16)fast_sin30(ac[mt2][g0 + i]);
            uint32_t hw0 = pack2(hh[0], hh[1]), hw1 = pack2(hh[2], hh[3]);
            uint32_t hw2 = pack2(hh[4], hh[5]), hw3 = pack2(hh[6], hh[7]);
            uint32_t rA = (uint32_t)__shfl_xor((int)(h ? hw0 : hw2), 32);
            uint32_t rB = (uint32_t)__shfl_xor((int)(h ? hw1 : hw3), 32);
            Xh[c].w[0] = h ? rA : hw0;  Xh[c].w[1] = h ? rB : hw1;
            Xh[c].w[2] = h ? hw2 : rA;  Xh[c].w[3] = h ? hw3 : rB;
        }
    };

    const f16x8* g3l = (const f16x8*)(wb + O_W3L);

#pragma unroll 1
    for (int iter = 0; iter < 16; ++iter) {
        const int pt = grp * 4096 + iter * 256 + wv * 32 + n;
        const float2 xy = ((const float2*)xg)[(size_t)b * N_ + pt];

        UF X1h[8], X1l[8];

        // ---- L1 (split, 1 chunk; bias folded at k=2 with B=1.0)
        {
            UF bh, bl;
            bh.w[0] = bh.w[1] = bh.w[2] = bh.w[3] = 0u;
            bl.w[0] = bl.w[1] = bl.w[2] = bl.w[3] = 0u;
            if (h == 0) {
                _Float16 xh = (_Float16)xy.x, yh = (_Float16)xy.y;
                _Float16 xl = (_Float16)(xy.x - (float)xh);
                _Float16 yl = (_Float16)(xy.y - (float)yh);
                bh.w[0] = pack2(xh, yh);
                bh.w[1] = 0x00003C00u;         // e2 = 1.0h
                bl.w[0] = pack2(xl, yl);
            }
#pragma unroll
            for (int half = 0; half < 2; ++half) {
                f32x16 a[2];
#pragma unroll
                for (int mt2 = 0; mt2 < 2; ++mt2) {
                    int mt = half * 2 + mt2;
                    f16x8 ah = *(const f16x8*)(smem + O_L1H + mt * 1024 + lb);
                    f16x8 al = *(const f16x8*)(smem + O_L1L + mt * 1024 + lb);
                    f32x16 z;
#pragma unroll
                    for (int i = 0; i < 16; ++i) z[i] = 0.f;
                    z = MFMA(ah, bh.v, z, 0, 0, 0);
                    z = MFMA(ah, bl.v, z, 0, 0, 0);
                    z = MFMA(al, bh.v, z, 0, 0, 0);
                    a[mt2] = z;
                }
                epi_split_half(a, X1h, X1l, half);
            }
        }

        // ---- L2 (split): hi + lo from LDS
        UF X2h[8], X2l[8];
#pragma unroll
        for (int half = 0; half < 2; ++half) {
            f32x16 a[2];
            init_bias_half(a, 0, half);
#pragma unroll
            for (int c = 0; c < 8; ++c)
#pragma unroll
                for (int mt2 = 0; mt2 < 2; ++mt2) {
                    int mt = half * 2 + mt2;
                    f16x8 ah = *(const f16x8*)(smem + O_L2H + (c * 4 + mt) * 1024 + lb);
                    f16x8 al = *(const f16x8*)(smem + O_W2L + (c * 4 + mt) * 1024 + lb);
                    a[mt2] = MFMA(ah, X1h[c].v, a[mt2], 0, 0, 0);
                    a[mt2] = MFMA(ah, X1l[c].v, a[mt2], 0, 0, 0);
                    a[mt2] = MFMA(al, X1h[c].v, a[mt2], 0, 0, 0);
                }
            epi_split_half(a, X2h, X2l, half);
        }

        // ---- L3 (split): hi from LDS, lo streamed from global (double-buffered)
        UF X3h[8];
#pragma unroll
        for (int half = 0; half < 2; ++half) {
            f32x16 a[2];
            init_bias_half(a, 1, half);
            f16x8 wl[2][2];
#pragma unroll
            for (int mt2 = 0; mt2 < 2; ++mt2)
                wl[0][mt2] = g3l[(half * 2 + mt2) * 64 + lane];
#pragma unroll
            for (int c = 0; c < 8; ++c) {
                if (c < 7) {
#pragma unroll
                    for (int mt2 = 0; mt2 < 2; ++mt2)
                        wl[(c + 1) & 1][mt2] = g3l[((c + 1) * 4 + half * 2 + mt2) * 64 + lane];
                }
#pragma unroll
                for (int mt2 = 0; mt2 < 2; ++mt2) {
                    int mt = half * 2 + mt2;
                    f16x8 ah = *(const f16x8*)(smem + O_L3H + (c * 4 + mt) * 1024 + lb);
                    a[mt2] = MFMA(ah, X2h[c].v, a[mt2], 0, 0, 0);
                    a[mt2] = MFMA(ah, X2l[c].v, a[mt2], 0, 0, 0);
                    a[mt2] = MFMA(wl[c & 1][mt2], X2h[c].v, a[mt2], 0, 0, 0);
                }
            }
            epi_hi_half(a, X3h, half);
        }

        // ---- L4 (plain f16)
        UF X4h[8];
#pragma unroll
        for (int half = 0; half < 2; ++half) {
            f32x16 a[2];
            init_bias_half(a, 2, half);
#pragma unroll
            for (int c = 0; c < 8; ++c)
#pragma unroll
                for (int mt2 = 0; mt2 < 2; ++mt2) {
                    int mt = half * 2 + mt2;
                    f16x8 ah = *(const f16x8*)(smem + O_L4H + (c * 4 + mt) * 1024 + lb);
                    a[mt2] = MFMA(ah, X3h[c].v, a[mt2], 0, 0, 0);
                }
            epi_hi_half(a, X4h, half);
        }

        // ---- L5 (plain f16, single M-tile, rows 3..31 zero)
        {
            f32x16 a5;
#pragma unroll
            for (int i = 0; i < 16; ++i) a5[i] = 0.f;
#pragma unroll
            for (int c = 0; c < 8; ++c) {
                f16x8 ah = *(const f16x8*)(smem + O_L5H + c * 1024 + lb);
                a5 = MFMA(ah, X4h[c].v, a5, 0, 0, 0);
            }
            if (h == 0) {
                size_t o = ((size_t)b * N_ + pt) * 3;
                struct F3 { float a, b, c; };
                F3 r; r.a = a5[0] + b5_0; r.b = a5[1] + b5_1; r.c = a5[2] + b5_2;
                *(F3*)(out + o) = r;
            }
        }
    }
}

extern "C" void kernel_launch(void* const* d_in, const int* in_sizes, int n_in,
                              void* d_out, int out_size, void* d_ws, size_t ws_size,
                              hipStream_t stream) {
    (void)in_sizes; (void)n_in; (void)out_size; (void)ws_size;
    const float* x = (const float*)d_in[0];
    const float* p = (const float*)d_in[1];
    float* o = (float*)d_out;
    char* ws = (char*)d_ws;   // needs 32 * 180224 = 5,767,168 B

    hipFuncSetAttribute(reinterpret_cast<const void*>(siren_main),
                        hipFuncAttributeMaxDynamicSharedMemorySize, LDSSET);
    siren_prep<<<dim3(108, 32), 64, 0, stream>>>(p, ws);
    siren_main<<<dim3(32, 8), 512, LDSSET, stream>>>(x, p, o, ws);
}

// Round 5
// 1764.312 us; speedup vs baseline: 1.0185x; 1.0185x over previous
//
#include <hip/hip_runtime.h>
#include <stdint.h>

// SIREN batched MLP, MI355X/gfx950 — round 5: fused layer transitions.
// r2-r4 failure mode: whole-layer X B-frag arrays (X_in 64 + X_out 64 VGPRs)
// exceeded the 128 arch-VGPR budget -> 3.3 GB scratch spill traffic.
// Fix: X is never materialized. Two layers' accumulators stay live (96 regs,
// AGPR-class); X flows in 4-chunk half-stages (32 arch regs, transient):
//   epi(acc_l half) -> S[4] -> accumulate into acc_{l+1} -> dead.
// Precision plan unchanged (verified r1-r4, absmax 0.0039): L1 split-MFMA,
// L2/L3 hi/lo split 3-term, L4 plain f16, L5 plain f16 M-padded.

typedef _Float16 f16x8 __attribute__((ext_vector_type(8)));
typedef float f32x16 __attribute__((ext_vector_type(16)));

#define MFMA __builtin_amdgcn_mfma_f32_32x32x16_f16

#define B_ 32
#define N_ 32768

// flat param offsets (floats)
#define OFF_W1 0
#define OFF_B1 256
#define OFF_W2 384
#define OFF_B2 16768
#define OFF_W3 16896
#define OFF_B3 33280
#define OFF_W4 33408
#define OFF_B4 49792
#define OFF_W5 49920
#define OFF_B5 50304
#define NPARAM 50307

// ws per-batch image offsets (bytes); frag-ordered: [c][mt][lane]*16B
#define O_L1H 0
#define O_L1L 4096
#define O_L2H 8192
#define O_W2L 40960
#define O_L3H 73728
#define O_L4H 106496
#define O_L5H 139264
#define LDSSET 147456          /* bytes staged to LDS */
#define O_W3L 147456           /* streamed from global (L2-resident) */
#define SWS   180224           /* per-batch ws stride */

__device__ __forceinline__ float fast_sin30(float v) {
    float t = v * 4.77464829275686f;   // 30 / (2*pi)
    t = t - floorf(t);
    return __builtin_amdgcn_sinf(t);
}

__device__ __forceinline__ uint32_t pack2(_Float16 a, _Float16 b) {
    union { _Float16 h[2]; uint32_t u; } x;
    x.h[0] = a; x.h[1] = b;
    return x.u;
}

// ---------------------------------------------------------------------------
// Prep: split params into f16 hi/lo, A-frag-ordered images (verified r1-r4).
// A-frag for 32x32x16_f16: lane l holds A[m = 32*mt + (l&31)][k = 16c + 8*(l>>5) + e].
// ---------------------------------------------------------------------------
__global__ __launch_bounds__(64) void siren_prep(const float* __restrict__ p0,
                                                 char* __restrict__ ws) {
    const int u = blockIdx.x;      // 0..107 image unit
    const int b = blockIdx.y;
    const int lane = threadIdx.x;
    const int jn = lane & 31;
    const int h = lane >> 5;
    const float* p = p0 + (size_t)b * NPARAM;
    char* wb = ws + (size_t)b * SWS;

    float v[8];
    size_t hoff = 0, loff = 0;
    bool haslo = false;

    if (u < 4) {                               // L1: [mt][lane], k=0:Wx 1:Wy 2:bias
        int mt = u, j = mt * 32 + jn;
#pragma unroll
        for (int e = 0; e < 8; ++e) {
            int k = h * 8 + e;
            v[e] = (k == 0) ? p[OFF_W1 + j * 2]
                 : (k == 1) ? p[OFF_W1 + j * 2 + 1]
                 : (k == 2) ? p[OFF_B1 + j] : 0.f;
        }
        hoff = O_L1H + (size_t)(mt * 64 + lane) * 16;
        loff = O_L1L + (size_t)(mt * 64 + lane) * 16;
        haslo = true;
    } else if (u < 100) {                      // L2/L3/L4: [c][mt][lane]
        int vv = u - 4;
        int layer = vv >> 5;                   // 0,1,2
        int r = vv & 31;
        int c = r >> 2, mt = r & 3;
        int j = mt * 32 + jn, kb = c * 16 + h * 8;
        int wOff = (layer == 0) ? OFF_W2 : (layer == 1) ? OFF_W3 : OFF_W4;
#pragma unroll
        for (int e = 0; e < 8; ++e) v[e] = p[wOff + j * 128 + kb + e];
        size_t idx = (size_t)((c * 4 + mt) * 64 + lane) * 16;
        if (layer == 0)      { hoff = O_L2H + idx; loff = O_W2L + idx; haslo = true; }
        else if (layer == 1) { hoff = O_L3H + idx; loff = O_W3L + idx; haslo = true; }
        else                 { hoff = O_L4H + idx; haslo = false; }
    } else {                                   // L5: [c][lane], rows 3..31 zero
        int c = u - 100, j = jn, kb = c * 16 + h * 8;
#pragma unroll
        for (int e = 0; e < 8; ++e) v[e] = (j < 3) ? p[OFF_W5 + j * 128 + kb + e] : 0.f;
        hoff = O_L5H + (size_t)(c * 64 + lane) * 16;
        haslo = false;
    }

    f16x8 hv, lv;
#pragma unroll
    for (int e = 0; e < 8; ++e) {
        _Float16 hh = (_Float16)v[e];
        hv[e] = hh;
        lv[e] = (_Float16)(v[e] - (float)hh);
    }
    *(f16x8*)(wb + hoff) = hv;
    if (haslo) *(f16x8*)(wb + loff) = lv;
}

// ---------------------------------------------------------------------------
// Main kernel: 512 threads = 8 waves (1 block/CU via 144 KB LDS).
// Wave processes 32 points/iter, 16 iters. Fused layer pipeline.
// ---------------------------------------------------------------------------
__global__ __launch_bounds__(512, 2)
void siren_main(const float* __restrict__ xg,
                const float* __restrict__ pg,
                float* __restrict__ out,
                const char* __restrict__ ws) {
    extern __shared__ __align__(16) char smem[];
    __shared__ float sBias[3][128];

    const int t = threadIdx.x;
    const int b = blockIdx.x;
    const int grp = blockIdx.y;
    const char* wb = ws + (size_t)b * SWS;
    const float* p = pg + (size_t)b * NPARAM;

    // stage weight images to LDS: 147456 B = 9216 float4 = 512 thr * 18
    {
        const float4* src = (const float4*)wb;
        float4* dst = (float4*)smem;
#pragma unroll
        for (int i = 0; i < 18; ++i) dst[t + i * 512] = src[t + i * 512];
    }
    if (t < 384) {
        int li = t >> 7, f = t & 127;
        sBias[li][f] = p[(li == 0 ? OFF_B2 : li == 1 ? OFF_B3 : OFF_B4) + f];
    }
    const float b5_0 = p[OFF_B5], b5_1 = p[OFF_B5 + 1], b5_2 = p[OFF_B5 + 2];
    __syncthreads();

    const int lane = t & 63;
    const int wv = t >> 6;
    const int n = lane & 31;
    const int h = lane >> 5;
    const int lb = lane * 16;

    union UF { f16x8 v; uint32_t w[4]; };

    // bias init, full layer (4 tiles): feat(reg r) = 32mt + (r&3)+8(r>>2)+4h
    auto init_bias = [&](f32x16 (&ac)[4], int li) {
#pragma unroll
        for (int mt = 0; mt < 4; ++mt)
#pragma unroll
            for (int rg = 0; rg < 4; ++rg) {
                float4 bb = *(const float4*)&sBias[li][mt * 32 + rg * 8 + h * 4];
                ac[mt][rg * 4 + 0] = bb.x; ac[mt][rg * 4 + 1] = bb.y;
                ac[mt][rg * 4 + 2] = bb.z; ac[mt][rg * 4 + 3] = bb.w;
            }
    };

    // epi: two acc tiles (one layer half) -> 4 B-frag chunk stages (hi+lo).
    // Relayout verified r1-r4: h=0 lanes keep elems 0-3 / receive partner's
    // 0-3 as 4-7; h=1 lanes receive partner's 4-7 as 0-3 / keep own 4-7.
    auto epi_split_pair = [&](f32x16& t0, f32x16& t1, UF (&Sh)[4], UF (&Sl)[4]) {
#pragma unroll
        for (int cc = 0; cc < 4; ++cc) {
            f32x16& ac = (cc < 2) ? t0 : t1;
            const int g0 = (cc & 1) * 8;
            _Float16 hh[8]; float lo[8];
#pragma unroll
            for (int i = 0; i < 8; ++i) {
                float s = fast_sin30(ac[g0 + i]);
                hh[i] = (_Float16)s;
                lo[i] = s - (float)hh[i];
            }
            uint32_t hw0 = pack2(hh[0], hh[1]), hw1 = pack2(hh[2], hh[3]);
            uint32_t hw2 = pack2(hh[4], hh[5]), hw3 = pack2(hh[6], hh[7]);
            _Float16 ll[8];
#pragma unroll
            for (int i = 0; i < 8; ++i) ll[i] = (_Float16)lo[i];
            uint32_t lw0 = pack2(ll[0], ll[1]), lw1 = pack2(ll[2], ll[3]);
            uint32_t lw2 = pack2(ll[4], ll[5]), lw3 = pack2(ll[6], ll[7]);

            uint32_t rA = (uint32_t)__shfl_xor((int)(h ? hw0 : hw2), 32);
            uint32_t rB = (uint32_t)__shfl_xor((int)(h ? hw1 : hw3), 32);
            Sh[cc].w[0] = h ? rA : hw0;  Sh[cc].w[1] = h ? rB : hw1;
            Sh[cc].w[2] = h ? hw2 : rA;  Sh[cc].w[3] = h ? hw3 : rB;

            uint32_t sA = (uint32_t)__shfl_xor((int)(h ? lw0 : lw2), 32);
            uint32_t sB = (uint32_t)__shfl_xor((int)(h ? lw1 : lw3), 32);
            Sl[cc].w[0] = h ? sA : lw0;  Sl[cc].w[1] = h ? sB : lw1;
            Sl[cc].w[2] = h ? lw2 : sA;  Sl[cc].w[3] = h ? lw3 : sB;
        }
    };

    auto epi_hi_pair = [&](f32x16& t0, f32x16& t1, UF (&Sh)[4]) {
#pragma unroll
        for (int cc = 0; cc < 4; ++cc) {
            f32x16& ac = (cc < 2) ? t0 : t1;
            const int g0 = (cc & 1) * 8;
            _Float16 hh[8];
#pragma unroll
            for (int i = 0; i < 8; ++i) hh[i] = (_Float16)fast_sin30(ac[g0 + i]);
            uint32_t hw0 = pack2(hh[0], hh[1]), hw1 = pack2(hh[2], hh[3]);
            uint32_t hw2 = pack2(hh[4], hh[5]), hw3 = pack2(hh[6], hh[7]);
            uint32_t rA = (uint32_t)__shfl_xor((int)(h ? hw0 : hw2), 32);
            uint32_t rB = (uint32_t)__shfl_xor((int)(h ? hw1 : hw3), 32);
            Sh[cc].w[0] = h ? rA : hw0;  Sh[cc].w[1] = h ? rB : hw1;
            Sh[cc].w[2] = h ? hw2 : rA;  Sh[cc].w[3] = h ? hw3 : rB;
        }
    };

    const f16x8* g3l = (const f16x8*)(wb + O_W3L);

#pragma unroll 1
    for (int iter = 0; iter < 16; ++iter) {
        const int pt = grp * 4096 + iter * 256 + wv * 32 + n;
        const float2 xy = ((const float2*)xg)[(size_t)b * N_ + pt];

        // ================= L1 -> L2 (fused) =================
        f32x16 A2[4];
        init_bias(A2, 0);
        {
            UF bh, bl;
            bh.w[0] = bh.w[1] = bh.w[2] = bh.w[3] = 0u;
            bl.w[0] = bl.w[1] = bl.w[2] = bl.w[3] = 0u;
            if (h == 0) {
                _Float16 xh = (_Float16)xy.x, yh = (_Float16)xy.y;
                _Float16 xl = (_Float16)(xy.x - (float)xh);
                _Float16 yl = (_Float16)(xy.y - (float)yh);
                bh.w[0] = pack2(xh, yh);
                bh.w[1] = 0x00003C00u;         // e2 = 1.0h (bias column)
                bl.w[0] = pack2(xl, yl);
            }
#pragma unroll
            for (int h1 = 0; h1 < 2; ++h1) {
                f32x16 a1[2];
#pragma unroll
                for (int mt2 = 0; mt2 < 2; ++mt2) {
                    int mt = h1 * 2 + mt2;
                    f16x8 ah = *(const f16x8*)(smem + O_L1H + mt * 1024 + lb);
                    f16x8 al = *(const f16x8*)(smem + O_L1L + mt * 1024 + lb);
                    f32x16 z;
#pragma unroll
                    for (int i = 0; i < 16; ++i) z[i] = 0.f;
                    z = MFMA(ah, bh.v, z, 0, 0, 0);
                    z = MFMA(ah, bl.v, z, 0, 0, 0);
                    z = MFMA(al, bh.v, z, 0, 0, 0);
                    a1[mt2] = z;
                }
                UF Sh[4], Sl[4];
                epi_split_pair(a1[0], a1[1], Sh, Sl);
#pragma unroll
                for (int cc = 0; cc < 4; ++cc) {
                    const int c = h1 * 4 + cc;
#pragma unroll
                    for (int mt = 0; mt < 4; ++mt) {
                        f16x8 ah = *(const f16x8*)(smem + O_L2H + (c * 4 + mt) * 1024 + lb);
                        f16x8 al = *(const f16x8*)(smem + O_W2L + (c * 4 + mt) * 1024 + lb);
                        A2[mt] = MFMA(ah, Sh[cc].v, A2[mt], 0, 0, 0);
                        A2[mt] = MFMA(ah, Sl[cc].v, A2[mt], 0, 0, 0);
                        A2[mt] = MFMA(al, Sh[cc].v, A2[mt], 0, 0, 0);
                    }
                }
            }
        }

        // ================= L2 -> L3 (fused; W3-lo streamed from global) =====
        f32x16 A3[4];
#pragma unroll
        for (int h1 = 0; h1 < 2; ++h1) {
            UF Sh[4], Sl[4];
            epi_split_pair(A2[h1 * 2], A2[h1 * 2 + 1], Sh, Sl);
            if (h1 == 0) init_bias(A3, 1);
            f16x8 wl[2][4];
#pragma unroll
            for (int mt = 0; mt < 4; ++mt)
                wl[0][mt] = g3l[((h1 * 4) * 4 + mt) * 64 + lane];
#pragma unroll
            for (int cc = 0; cc < 4; ++cc) {
                const int c = h1 * 4 + cc;
                if (cc < 3) {
#pragma unroll
                    for (int mt = 0; mt < 4; ++mt)
                        wl[(cc + 1) & 1][mt] = g3l[((c + 1) * 4 + mt) * 64 + lane];
                }
#pragma unroll
                for (int mt = 0; mt < 4; ++mt) {
                    f16x8 ah = *(const f16x8*)(smem + O_L3H + (c * 4 + mt) * 1024 + lb);
                    A3[mt] = MFMA(ah, Sh[cc].v, A3[mt], 0, 0, 0);
                    A3[mt] = MFMA(ah, Sl[cc].v, A3[mt], 0, 0, 0);
                    A3[mt] = MFMA(wl[cc & 1][mt], Sh[cc].v, A3[mt], 0, 0, 0);
                }
            }
        }

        // ================= L3 -> L4 (fused; plain f16) ======================
        f32x16 A4[4];
#pragma unroll
        for (int h1 = 0; h1 < 2; ++h1) {
            UF Sh[4];
            epi_hi_pair(A3[h1 * 2], A3[h1 * 2 + 1], Sh);
            if (h1 == 0) init_bias(A4, 2);
#pragma unroll
            for (int cc = 0; cc < 4; ++cc) {
                const int c = h1 * 4 + cc;
#pragma unroll
                for (int mt = 0; mt < 4; ++mt) {
                    f16x8 ah = *(const f16x8*)(smem + O_L4H + (c * 4 + mt) * 1024 + lb);
                    A4[mt] = MFMA(ah, Sh[cc].v, A4[mt], 0, 0, 0);
                }
            }
        }

        // ================= L4 -> L5 (fused; M-padded single tile) ===========
        f32x16 a5;
#pragma unroll
        for (int i = 0; i < 16; ++i) a5[i] = 0.f;
#pragma unroll
        for (int h1 = 0; h1 < 2; ++h1) {
            UF Sh[4];
            epi_hi_pair(A4[h1 * 2], A4[h1 * 2 + 1], Sh);
#pragma unroll
            for (int cc = 0; cc < 4; ++cc) {
                const int c = h1 * 4 + cc;
                f16x8 ah = *(const f16x8*)(smem + O_L5H + c * 1024 + lb);
                a5 = MFMA(ah, Sh[cc].v, a5, 0, 0, 0);
            }
        }

        if (h == 0) {
            size_t o = ((size_t)b * N_ + pt) * 3;
            struct F3 { float a, b, c; };
            F3 r; r.a = a5[0] + b5_0; r.b = a5[1] + b5_1; r.c = a5[2] + b5_2;
            *(F3*)(out + o) = r;
        }
    }
}

extern "C" void kernel_launch(void* const* d_in, const int* in_sizes, int n_in,
                              void* d_out, int out_size, void* d_ws, size_t ws_size,
                              hipStream_t stream) {
    (void)in_sizes; (void)n_in; (void)out_size; (void)ws_size;
    const float* x = (const float*)d_in[0];
    const float* p = (const float*)d_in[1];
    float* o = (float*)d_out;
    char* ws = (char*)d_ws;   // needs 32 * 180224 = 5,767,168 B

    hipFuncSetAttribute(reinterpret_cast<const void*>(siren_main),
                        hipFuncAttributeMaxDynamicSharedMemorySize, LDSSET);
    siren_prep<<<dim3(108, 32), 64, 0, stream>>>(p, ws);
    siren_main<<<dim3(32, 8), 512, LDSSET, stream>>>(x, p, o, ws);
}

// Round 6
// 1748.739 us; speedup vs baseline: 1.0276x; 1.0089x over previous
//
#include <hip/hip_runtime.h>
#include <stdint.h>

// SIREN batched MLP, MI355X/gfx950 — round 6: fused pipeline with 1-chunk
// X stages. r2-r5 failure: acc-class peak is 128 AGPRs (two layers' acc live
// at each transition) -> arch partition capped at 128; arch demand was ~140+
// (4-chunk stages 32 + W3lo ping-pong 32 + wide ds/epi windows) -> ~40 regs
// spilled, re-read ~8x = 3.25 GB scratch traffic. Fix: stage = ONE chunk
// (8 arch regs), consumed immediately by the 4 next-layer tiles, then dead.
// Arch demand ~90 < 128. Precision unchanged (verified r1-r5, absmax 0.0039).

typedef _Float16 f16x8 __attribute__((ext_vector_type(8)));
typedef float f32x16 __attribute__((ext_vector_type(16)));

#define MFMA __builtin_amdgcn_mfma_f32_32x32x16_f16

#define B_ 32
#define N_ 32768

// flat param offsets (floats)
#define OFF_W1 0
#define OFF_B1 256
#define OFF_W2 384
#define OFF_B2 16768
#define OFF_W3 16896
#define OFF_B3 33280
#define OFF_W4 33408
#define OFF_B4 49792
#define OFF_W5 49920
#define OFF_B5 50304
#define NPARAM 50307

// ws per-batch image offsets (bytes); frag-ordered: [c][mt][lane]*16B
#define O_L1H 0
#define O_L1L 4096
#define O_L2H 8192
#define O_W2L 40960
#define O_L3H 73728
#define O_L4H 106496
#define O_L5H 139264
#define LDSSET 147456          /* bytes staged to LDS */
#define O_W3L 147456           /* streamed from global (L2-resident) */
#define SWS   180224           /* per-batch ws stride */

__device__ __forceinline__ float fast_sin30(float v) {
    float t = v * 4.77464829275686f;   // 30 / (2*pi)
    t = t - floorf(t);
    return __builtin_amdgcn_sinf(t);
}

__device__ __forceinline__ uint32_t pack2(_Float16 a, _Float16 b) {
    union { _Float16 h[2]; uint32_t u; } x;
    x.h[0] = a; x.h[1] = b;
    return x.u;
}

// ---------------------------------------------------------------------------
// Prep: split params into f16 hi/lo, A-frag-ordered images (verified r1-r5).
// A-frag for 32x32x16_f16: lane l holds A[m = 32*mt + (l&31)][k = 16c + 8*(l>>5) + e].
// ---------------------------------------------------------------------------
__global__ __launch_bounds__(64) void siren_prep(const float* __restrict__ p0,
                                                 char* __restrict__ ws) {
    const int u = blockIdx.x;      // 0..107 image unit
    const int b = blockIdx.y;
    const int lane = threadIdx.x;
    const int jn = lane & 31;
    const int h = lane >> 5;
    const float* p = p0 + (size_t)b * NPARAM;
    char* wb = ws + (size_t)b * SWS;

    float v[8];
    size_t hoff = 0, loff = 0;
    bool haslo = false;

    if (u < 4) {                               // L1: [mt][lane], k=0:Wx 1:Wy 2:bias
        int mt = u, j = mt * 32 + jn;
#pragma unroll
        for (int e = 0; e < 8; ++e) {
            int k = h * 8 + e;
            v[e] = (k == 0) ? p[OFF_W1 + j * 2]
                 : (k == 1) ? p[OFF_W1 + j * 2 + 1]
                 : (k == 2) ? p[OFF_B1 + j] : 0.f;
        }
        hoff = O_L1H + (size_t)(mt * 64 + lane) * 16;
        loff = O_L1L + (size_t)(mt * 64 + lane) * 16;
        haslo = true;
    } else if (u < 100) {                      // L2/L3/L4: [c][mt][lane]
        int vv = u - 4;
        int layer = vv >> 5;                   // 0,1,2
        int r = vv & 31;
        int c = r >> 2, mt = r & 3;
        int j = mt * 32 + jn, kb = c * 16 + h * 8;
        int wOff = (layer == 0) ? OFF_W2 : (layer == 1) ? OFF_W3 : OFF_W4;
#pragma unroll
        for (int e = 0; e < 8; ++e) v[e] = p[wOff + j * 128 + kb + e];
        size_t idx = (size_t)((c * 4 + mt) * 64 + lane) * 16;
        if (layer == 0)      { hoff = O_L2H + idx; loff = O_W2L + idx; haslo = true; }
        else if (layer == 1) { hoff = O_L3H + idx; loff = O_W3L + idx; haslo = true; }
        else                 { hoff = O_L4H + idx; haslo = false; }
    } else {                                   // L5: [c][lane], rows 3..31 zero
        int c = u - 100, j = jn, kb = c * 16 + h * 8;
#pragma unroll
        for (int e = 0; e < 8; ++e) v[e] = (j < 3) ? p[OFF_W5 + j * 128 + kb + e] : 0.f;
        hoff = O_L5H + (size_t)(c * 64 + lane) * 16;
        haslo = false;
    }

    f16x8 hv, lv;
#pragma unroll
    for (int e = 0; e < 8; ++e) {
        _Float16 hh = (_Float16)v[e];
        hv[e] = hh;
        lv[e] = (_Float16)(v[e] - (float)hh);
    }
    *(f16x8*)(wb + hoff) = hv;
    if (haslo) *(f16x8*)(wb + loff) = lv;
}

// ---------------------------------------------------------------------------
// Main kernel: 512 threads = 8 waves (1 block/CU via 144 KB LDS).
// Wave processes 32 points/iter, 16 iters. Fused pipeline, 1-chunk stages.
// ---------------------------------------------------------------------------
__global__ __launch_bounds__(512, 2)
void siren_main(const float* __restrict__ xg,
                const float* __restrict__ pg,
                float* __restrict__ out,
                const char* __restrict__ ws) {
    extern __shared__ __align__(16) char smem[];
    __shared__ __align__(16) float sBias[3][128];

    const int t = threadIdx.x;
    const int b = blockIdx.x;
    const int grp = blockIdx.y;
    const char* wb = ws + (size_t)b * SWS;
    const float* p = pg + (size_t)b * NPARAM;

    // stage weight images to LDS: 147456 B = 9216 float4 = 512 thr * 18
    // unroll capped at 6 -> <=24 regs in flight (don't inflate arch pressure)
    {
        const float4* src = (const float4*)wb;
        float4* dst = (float4*)smem;
#pragma unroll 6
        for (int i = 0; i < 18; ++i) dst[t + i * 512] = src[t + i * 512];
    }
    if (t < 384) {
        int li = t >> 7, f = t & 127;
        sBias[li][f] = p[(li == 0 ? OFF_B2 : li == 1 ? OFF_B3 : OFF_B4) + f];
    }
    const float b5_0 = p[OFF_B5], b5_1 = p[OFF_B5 + 1], b5_2 = p[OFF_B5 + 2];
    __syncthreads();

    const int lane = t & 63;
    const int wv = t >> 6;
    const int n = lane & 31;
    const int h = lane >> 5;
    const int lb = lane * 16;

    union UF { f16x8 v; uint32_t w[4]; };

    // bias init, full layer (4 tiles): feat(reg r) = 32mt + (r&3)+8(r>>2)+4h
    auto init_bias = [&](f32x16 (&ac)[4], int li) {
#pragma unroll
        for (int mt = 0; mt < 4; ++mt)
#pragma unroll
            for (int rg = 0; rg < 4; ++rg) {
                float4 bb = *(const float4*)&sBias[li][mt * 32 + rg * 8 + h * 4];
                ac[mt][rg * 4 + 0] = bb.x; ac[mt][rg * 4 + 1] = bb.y;
                ac[mt][rg * 4 + 2] = bb.z; ac[mt][rg * 4 + 3] = bb.w;
            }
    };

    // epi of ONE chunk: 8 acc elems (g0=0 or 8) -> B-frag stage (hi+lo).
    // Relayout verified r1-r5: h=0 lanes keep elems 0-3 / receive partner's
    // as 4-7; h=1 lanes receive partner's as 0-3 / keep own 4-7.
    auto epi_split_chunk = [&](const f32x16& ac, int g0, UF& Sh, UF& Sl) {
        _Float16 hh[8]; float lo[8];
#pragma unroll
        for (int i = 0; i < 8; ++i) {
            float s = fast_sin30(ac[g0 + i]);
            hh[i] = (_Float16)s;
            lo[i] = s - (float)hh[i];
        }
        uint32_t hw0 = pack2(hh[0], hh[1]), hw1 = pack2(hh[2], hh[3]);
        uint32_t hw2 = pack2(hh[4], hh[5]), hw3 = pack2(hh[6], hh[7]);
        _Float16 ll[8];
#pragma unroll
        for (int i = 0; i < 8; ++i) ll[i] = (_Float16)lo[i];
        uint32_t lw0 = pack2(ll[0], ll[1]), lw1 = pack2(ll[2], ll[3]);
        uint32_t lw2 = pack2(ll[4], ll[5]), lw3 = pack2(ll[6], ll[7]);

        uint32_t rA = (uint32_t)__shfl_xor((int)(h ? hw0 : hw2), 32);
        uint32_t rB = (uint32_t)__shfl_xor((int)(h ? hw1 : hw3), 32);
        Sh.w[0] = h ? rA : hw0;  Sh.w[1] = h ? rB : hw1;
        Sh.w[2] = h ? hw2 : rA;  Sh.w[3] = h ? hw3 : rB;

        uint32_t sA = (uint32_t)__shfl_xor((int)(h ? lw0 : lw2), 32);
        uint32_t sB = (uint32_t)__shfl_xor((int)(h ? lw1 : lw3), 32);
        Sl.w[0] = h ? sA : lw0;  Sl.w[1] = h ? sB : lw1;
        Sl.w[2] = h ? lw2 : sA;  Sl.w[3] = h ? lw3 : sB;
    };

    auto epi_hi_chunk = [&](const f32x16& ac, int g0, UF& Sh) {
        _Float16 hh[8];
#pragma unroll
        for (int i = 0; i < 8; ++i) hh[i] = (_Float16)fast_sin30(ac[g0 + i]);
        uint32_t hw0 = pack2(hh[0], hh[1]), hw1 = pack2(hh[2], hh[3]);
        uint32_t hw2 = pack2(hh[4], hh[5]), hw3 = pack2(hh[6], hh[7]);
        uint32_t rA = (uint32_t)__shfl_xor((int)(h ? hw0 : hw2), 32);
        uint32_t rB = (uint32_t)__shfl_xor((int)(h ? hw1 : hw3), 32);
        Sh.w[0] = h ? rA : hw0;  Sh.w[1] = h ? rB : hw1;
        Sh.w[2] = h ? hw2 : rA;  Sh.w[3] = h ? hw3 : rB;
    };

    const f16x8* g3l = (const f16x8*)(wb + O_W3L);

#pragma unroll 1
    for (int iter = 0; iter < 16; ++iter) {
        const int pt = grp * 4096 + iter * 256 + wv * 32 + n;
        const float2 xy = ((const float2*)xg)[(size_t)b * N_ + pt];

        // ================= L1 -> L2 (fused, chunk-at-a-time) ================
        f32x16 A2[4];
        init_bias(A2, 0);
        {
            UF bh, bl;
            bh.w[0] = bh.w[1] = bh.w[2] = bh.w[3] = 0u;
            bl.w[0] = bl.w[1] = bl.w[2] = bl.w[3] = 0u;
            if (h == 0) {
                _Float16 xh = (_Float16)xy.x, yh = (_Float16)xy.y;
                _Float16 xl = (_Float16)(xy.x - (float)xh);
                _Float16 yl = (_Float16)(xy.y - (float)yh);
                bh.w[0] = pack2(xh, yh);
                bh.w[1] = 0x00003C00u;         // e2 = 1.0h (bias column)
                bl.w[0] = pack2(xl, yl);
            }
#pragma unroll
            for (int mt1 = 0; mt1 < 4; ++mt1) {
                f16x8 ah1 = *(const f16x8*)(smem + O_L1H + mt1 * 1024 + lb);
                f16x8 al1 = *(const f16x8*)(smem + O_L1L + mt1 * 1024 + lb);
                f32x16 z;
#pragma unroll
                for (int i = 0; i < 16; ++i) z[i] = 0.f;
                z = MFMA(ah1, bh.v, z, 0, 0, 0);
                z = MFMA(ah1, bl.v, z, 0, 0, 0);
                z = MFMA(al1, bh.v, z, 0, 0, 0);
#pragma unroll
                for (int s = 0; s < 2; ++s) {
                    const int c = mt1 * 2 + s;
                    UF Sh, Sl;
                    epi_split_chunk(z, s * 8, Sh, Sl);
#pragma unroll
                    for (int m2 = 0; m2 < 4; ++m2) {
                        f16x8 ah = *(const f16x8*)(smem + O_L2H + (c * 4 + m2) * 1024 + lb);
                        f16x8 al = *(const f16x8*)(smem + O_W2L + (c * 4 + m2) * 1024 + lb);
                        A2[m2] = MFMA(ah, Sh.v, A2[m2], 0, 0, 0);
                        A2[m2] = MFMA(ah, Sl.v, A2[m2], 0, 0, 0);
                        A2[m2] = MFMA(al, Sh.v, A2[m2], 0, 0, 0);
                    }
                }
            }
        }

        // ================= L2 -> L3 (fused; W3-lo streamed, ping-pong) ======
        f32x16 A3[4];
        init_bias(A3, 1);
        {
            f16x8 wl[2][4];
#pragma unroll
            for (int m2 = 0; m2 < 4; ++m2) wl[0][m2] = g3l[m2 * 64 + lane];
#pragma unroll
            for (int mt = 0; mt < 4; ++mt)
#pragma unroll
                for (int s = 0; s < 2; ++s) {
                    const int c = mt * 2 + s;
                    UF Sh, Sl;
                    epi_split_chunk(A2[mt], s * 8, Sh, Sl);
                    if (c < 7) {
#pragma unroll
                        for (int m2 = 0; m2 < 4; ++m2)
                            wl[(c + 1) & 1][m2] = g3l[((c + 1) * 4 + m2) * 64 + lane];
                    }
#pragma unroll
                    for (int m2 = 0; m2 < 4; ++m2) {
                        f16x8 ah = *(const f16x8*)(smem + O_L3H + (c * 4 + m2) * 1024 + lb);
                        A3[m2] = MFMA(ah, Sh.v, A3[m2], 0, 0, 0);
                        A3[m2] = MFMA(ah, Sl.v, A3[m2], 0, 0, 0);
                        A3[m2] = MFMA(wl[c & 1][m2], Sh.v, A3[m2], 0, 0, 0);
                    }
                }
        }

        // ================= L3 -> L4 (fused; plain f16) ======================
        f32x16 A4[4];
        init_bias(A4, 2);
#pragma unroll
        for (int mt = 0; mt < 4; ++mt)
#pragma unroll
            for (int s = 0; s < 2; ++s) {
                const int c = mt * 2 + s;
                UF Sh;
                epi_hi_chunk(A3[mt], s * 8, Sh);
#pragma unroll
                for (int m2 = 0; m2 < 4; ++m2) {
                    f16x8 ah = *(const f16x8*)(smem + O_L4H + (c * 4 + m2) * 1024 + lb);
                    A4[m2] = MFMA(ah, Sh.v, A4[m2], 0, 0, 0);
                }
            }

        // ================= L4 -> L5 (fused; M-padded single tile) ===========
        f32x16 a5;
#pragma unroll
        for (int i = 0; i < 16; ++i) a5[i] = 0.f;
#pragma unroll
        for (int mt = 0; mt < 4; ++mt)
#pragma unroll
            for (int s = 0; s < 2; ++s) {
                const int c = mt * 2 + s;
                UF Sh;
                epi_hi_chunk(A4[mt], s * 8, Sh);
                f16x8 ah = *(const f16x8*)(smem + O_L5H + c * 1024 + lb);
                a5 = MFMA(ah, Sh.v, a5, 0, 0, 0);
            }

        if (h == 0) {
            size_t o = ((size_t)b * N_ + pt) * 3;
            struct F3 { float a, b, c; };
            F3 r; r.a = a5[0] + b5_0; r.b = a5[1] + b5_1; r.c = a5[2] + b5_2;
            *(F3*)(out + o) = r;
        }
    }
}

extern "C" void kernel_launch(void* const* d_in, const int* in_sizes, int n_in,
                              void* d_out, int out_size, void* d_ws, size_t ws_size,
                              hipStream_t stream) {
    (void)in_sizes; (void)n_in; (void)out_size; (void)ws_size;
    const float* x = (const float*)d_in[0];
    const float* p = (const float*)d_in[1];
    float* o = (float*)d_out;
    char* ws = (char*)d_ws;   // needs 32 * 180224 = 5,767,168 B

    hipFuncSetAttribute(reinterpret_cast<const void*>(siren_main),
                        hipFuncAttributeMaxDynamicSharedMemorySize, LDSSET);
    siren_prep<<<dim3(108, 32), 64, 0, stream>>>(p, ws);
    siren_main<<<dim3(32, 8), 512, LDSSET, stream>>>(x, p, o, ws);
}

// Round 7
// 299.927 us; speedup vs baseline: 5.9914x; 5.8306x over previous
//
#include <hip/hip_runtime.h>
#include <stdint.h>

// SIREN batched MLP, MI355X/gfx950 — round 7: 16x16x32 MFMA + feature-permuted
// k-layout (zero-shuffle epilogue). r2-r6: 32x32 tiles forced 128 acc regs
// (two live layers) -> arch side of the 256-reg budget overflowed -> 3.3 GB
// scratch traffic at VGPR_Count=128. 16x16 halves acc to 64 and the
// permutation phi_c(k) = 16c + 64*(e>=4) + 4g + (e&3) makes C/D -> next-B-frag
// a pure per-lane repack (chunk c = tiles {c, c+4} regs 0-3).
// Precision: L1 fp32 VALU, L2 3-term hi/lo, L3 2-term (W3-lo dropped, est
// +0.004 absmax), L4 plain, L5 plain M-padded. Expected absmax ~0.007.

typedef _Float16 f16x8 __attribute__((ext_vector_type(8)));
typedef float f32x4 __attribute__((ext_vector_type(4)));

#define MFMA16 __builtin_amdgcn_mfma_f32_16x16x32_f16

#define B_ 32
#define N_ 32768

// flat param offsets (floats)
#define OFF_W1 0
#define OFF_B1 256
#define OFF_W2 384
#define OFF_B2 16768
#define OFF_W3 16896
#define OFF_B3 33280
#define OFF_W4 33408
#define OFF_B4 49792
#define OFF_W5 49920
#define OFF_B5 50304
#define NPARAM 50307

// ws / LDS image offsets (bytes). A-frag images: [c][mt][lane]*16B.
#define WO_L2H 0
#define WO_W2L 32768
#define WO_L3H 65536
#define WO_L4H 98304
#define WO_L5H 131072      /* 4 KB: single M-tile, rows 3..15 zero */
#define WO_W1X 135168      /* 128 floats, slot-ordered s = c*32 + k_local */
#define WO_W1Y 135680
#define WO_B1S 136192
#define SWS    136704      /* per-batch ws stride; also bytes staged to LDS */
#define LDS_BIAS 136704    /* 3*128 floats */
#define LDSSET 138240

__device__ __forceinline__ float fast_sin30(float v) {
    float t = v * 4.77464829275686f;   // 30 / (2*pi)
    t = t - floorf(t);
    return __builtin_amdgcn_sinf(t);
}

__device__ __forceinline__ uint32_t pack2(_Float16 a, _Float16 b) {
    union { _Float16 h[2]; uint32_t u; } x;
    x.h[0] = a; x.h[1] = b;
    return x.u;
}

// ---------------------------------------------------------------------------
// Prep. 16x16x32 A-frag: lane l holds A[m = 16mt + (l&15)][k_local = 8*(l>>4)+e]
// within K-chunk c; input feature f = phi_c(k) = 16c + 64*(e>=4) + 4g + (e&3),
// i.e. e=0..3 -> f0+e with f0 = 16c+4g; e=4..7 -> f0+64+(e-4). Two float4 loads.
// ---------------------------------------------------------------------------
__global__ __launch_bounds__(64) void siren_prep(const float* __restrict__ p0,
                                                 char* __restrict__ ws) {
    const int u = blockIdx.x;      // 0..101
    const int b = blockIdx.y;
    const int l = threadIdx.x;
    const float* p = p0 + (size_t)b * NPARAM;
    char* wb = ws + (size_t)b * SWS;

    if (u < 100) {
        int li, c, mt;
        if (u < 96) { li = u >> 5; int r = u & 31; c = r >> 3; mt = r & 7; }
        else        { li = 3; c = u - 96; mt = 0; }
        const int m = l & 15, gA = l >> 4;
        int wOff; size_t dstH; bool lo = false;
        if (li == 0)      { wOff = OFF_W2; dstH = WO_L2H; lo = true; }
        else if (li == 1) { wOff = OFF_W3; dstH = WO_L3H; }
        else if (li == 2) { wOff = OFF_W4; dstH = WO_L4H; }
        else              { wOff = OFF_W5; dstH = WO_L5H; }
        const int j = (li == 3) ? m : (16 * mt + m);
        const int f0 = 16 * c + 4 * gA;

        float v[8];
        if (li == 3 && m >= 3) {
#pragma unroll
            for (int e = 0; e < 8; ++e) v[e] = 0.f;
        } else {
            float4 a  = *(const float4*)(p + wOff + j * 128 + f0);
            float4 bq = *(const float4*)(p + wOff + j * 128 + f0 + 64);
            v[0] = a.x;  v[1] = a.y;  v[2] = a.z;  v[3] = a.w;
            v[4] = bq.x; v[5] = bq.y; v[6] = bq.z; v[7] = bq.w;
        }
        f16x8 hv, lv;
#pragma unroll
        for (int e = 0; e < 8; ++e) {
            _Float16 hh = (_Float16)v[e];
            hv[e] = hh;
            lv[e] = (_Float16)(v[e] - (float)hh);
        }
        size_t idx = (li == 3) ? (size_t)(c * 64 + l) * 16
                               : (size_t)((c * 8 + mt) * 64 + l) * 16;
        *(f16x8*)(wb + dstH + idx) = hv;
        if (lo) *(f16x8*)(wb + WO_W2L + idx) = lv;
    } else {
        // W1/B1 in slot order: s = c*32 + k_local
        int s = (u - 100) * 64 + l;            // 0..127
        int c = s >> 5, k = s & 31, gq = k >> 3, e = k & 7;
        int f = 16 * c + ((e & 4) ? 64 : 0) + 4 * gq + (e & 3);
        ((float*)(wb + WO_W1X))[s] = p[OFF_W1 + 2 * f];
        ((float*)(wb + WO_W1Y))[s] = p[OFF_W1 + 2 * f + 1];
        ((float*)(wb + WO_B1S))[s] = p[OFF_B1 + f];
    }
}

// ---------------------------------------------------------------------------
// Main: 512 threads = 8 waves, 1 block/CU (138 KB LDS). Wave does 16 points
// per iter, 32 iters -> 4096 points per block. Grid (32 batches, 8 slabs).
// ---------------------------------------------------------------------------
__global__ __launch_bounds__(512, 2)
void siren_main(const float* __restrict__ xg,
                const float* __restrict__ pg,
                float* __restrict__ out,
                const char* __restrict__ ws) {
    extern __shared__ __align__(16) char smem[];

    const int t = threadIdx.x;
    const int b = blockIdx.x;
    const int grp = blockIdx.y;
    const char* wb = ws + (size_t)b * SWS;
    const float* p = pg + (size_t)b * NPARAM;

    {
        const float4* src = (const float4*)wb;
        float4* dst = (float4*)smem;
        for (int i = t; i < SWS / 16; i += 512) dst[i] = src[i];
    }
    float* sB = (float*)(smem + LDS_BIAS);
    if (t < 384) {
        int li = t >> 7, f = t & 127;
        sB[t] = p[(li == 0 ? OFF_B2 : li == 1 ? OFF_B3 : OFF_B4) + f];
    }
    const float b5_0 = p[OFF_B5], b5_1 = p[OFF_B5 + 1], b5_2 = p[OFF_B5 + 2];
    __syncthreads();

    const int lane = t & 63;
    const int wv = t >> 6;
    const int n = lane & 15;
    const int g = lane >> 4;
    const int lb = lane * 16;

    const char* L2Hp = smem + WO_L2H;
    const char* W2Lp = smem + WO_W2L;
    const char* L3Hp = smem + WO_L3H;
    const char* L4Hp = smem + WO_L4H;
    const char* L5Hp = smem + WO_L5H;
    const float* W1X = (const float*)(smem + WO_W1X);
    const float* W1Y = (const float*)(smem + WO_W1Y);
    const float* B1S = (const float*)(smem + WO_B1S);

    union UF { f16x8 v; uint32_t w[4]; };

    auto initb = [&](f32x4 (&A)[8], int li) {
#pragma unroll
        for (int mt = 0; mt < 8; ++mt)
            A[mt] = *(const f32x4*)&sB[li * 128 + 16 * mt + 4 * g];
    };

    // epi: acc -> B-frag chunk c = {tile c regs 0-3 (e0-3), tile c+4 regs 0-3 (e4-7)}
    auto epi_split = [&](const f32x4 (&A)[8], UF (&Xh)[4], UF (&Xl)[4]) {
#pragma unroll
        for (int c = 0; c < 4; ++c) {
            _Float16 hh[8], ll[8];
#pragma unroll
            for (int r = 0; r < 4; ++r) {
                float s = fast_sin30(A[c][r]);
                hh[r] = (_Float16)s; ll[r] = (_Float16)(s - (float)hh[r]);
                float s2 = fast_sin30(A[c + 4][r]);
                hh[4 + r] = (_Float16)s2; ll[4 + r] = (_Float16)(s2 - (float)hh[4 + r]);
            }
            Xh[c].w[0] = pack2(hh[0], hh[1]); Xh[c].w[1] = pack2(hh[2], hh[3]);
            Xh[c].w[2] = pack2(hh[4], hh[5]); Xh[c].w[3] = pack2(hh[6], hh[7]);
            Xl[c].w[0] = pack2(ll[0], ll[1]); Xl[c].w[1] = pack2(ll[2], ll[3]);
            Xl[c].w[2] = pack2(ll[4], ll[5]); Xl[c].w[3] = pack2(ll[6], ll[7]);
        }
    };

    auto epi_hi = [&](const f32x4 (&A)[8], UF (&Xh)[4]) {
#pragma unroll
        for (int c = 0; c < 4; ++c) {
            _Float16 hh[8];
#pragma unroll
            for (int r = 0; r < 4; ++r) {
                hh[r]     = (_Float16)fast_sin30(A[c][r]);
                hh[4 + r] = (_Float16)fast_sin30(A[c + 4][r]);
            }
            Xh[c].w[0] = pack2(hh[0], hh[1]); Xh[c].w[1] = pack2(hh[2], hh[3]);
            Xh[c].w[2] = pack2(hh[4], hh[5]); Xh[c].w[3] = pack2(hh[6], hh[7]);
        }
    };

#pragma unroll 1
    for (int iter = 0; iter < 32; ++iter) {
        // block cross-iteration LDS-load hoisting (W1/bias reads would
        // otherwise be LICM'd into ~100 permanently-live regs)
        asm volatile("" ::: "memory");

        const int pt = grp * 4096 + iter * 128 + wv * 16 + n;
        const float2 xy = ((const float2*)xg)[(size_t)b * N_ + pt];

        // ---- L1: fp32 VALU straight into B-frag slots (slot-ordered W1)
        UF X1h[4], X1l[4];
#pragma unroll
        for (int c = 0; c < 4; ++c) {
            const int s0 = c * 32 + g * 8;
            float4 wxa = *(const float4*)(W1X + s0), wxb = *(const float4*)(W1X + s0 + 4);
            float4 wya = *(const float4*)(W1Y + s0), wyb = *(const float4*)(W1Y + s0 + 4);
            float4 bba = *(const float4*)(B1S + s0), bbb = *(const float4*)(B1S + s0 + 4);
            float wx[8] = {wxa.x, wxa.y, wxa.z, wxa.w, wxb.x, wxb.y, wxb.z, wxb.w};
            float wy[8] = {wya.x, wya.y, wya.z, wya.w, wyb.x, wyb.y, wyb.z, wyb.w};
            float bc[8] = {bba.x, bba.y, bba.z, bba.w, bbb.x, bbb.y, bbb.z, bbb.w};
            _Float16 hh[8], ll[8];
#pragma unroll
            for (int e = 0; e < 8; ++e) {
                float a = fmaf(xy.x, wx[e], fmaf(xy.y, wy[e], bc[e]));
                float s = fast_sin30(a);
                hh[e] = (_Float16)s;
                ll[e] = (_Float16)(s - (float)hh[e]);
            }
            X1h[c].w[0] = pack2(hh[0], hh[1]); X1h[c].w[1] = pack2(hh[2], hh[3]);
            X1h[c].w[2] = pack2(hh[4], hh[5]); X1h[c].w[3] = pack2(hh[6], hh[7]);
            X1l[c].w[0] = pack2(ll[0], ll[1]); X1l[c].w[1] = pack2(ll[2], ll[3]);
            X1l[c].w[2] = pack2(ll[4], ll[5]); X1l[c].w[3] = pack2(ll[6], ll[7]);
        }

        // ---- L2: 3-term hi/lo split
        f32x4 A2[8];
        initb(A2, 0);
#pragma unroll
        for (int c = 0; c < 4; ++c)
#pragma unroll
            for (int mt = 0; mt < 8; ++mt) {
                f16x8 ah = *(const f16x8*)(L2Hp + (c * 8 + mt) * 1024 + lb);
                f16x8 al = *(const f16x8*)(W2Lp + (c * 8 + mt) * 1024 + lb);
                A2[mt] = MFMA16(ah, X1h[c].v, A2[mt], 0, 0, 0);
                A2[mt] = MFMA16(ah, X1l[c].v, A2[mt], 0, 0, 0);
                A2[mt] = MFMA16(al, X1h[c].v, A2[mt], 0, 0, 0);
            }

        UF X2h[4], X2l[4];
        epi_split(A2, X2h, X2l);

        // ---- L3: 2-term (W3 hi only; X2 split kept)
        f32x4 A3[8];
        initb(A3, 1);
#pragma unroll
        for (int c = 0; c < 4; ++c)
#pragma unroll
            for (int mt = 0; mt < 8; ++mt) {
                f16x8 ah = *(const f16x8*)(L3Hp + (c * 8 + mt) * 1024 + lb);
                A3[mt] = MFMA16(ah, X2h[c].v, A3[mt], 0, 0, 0);
                A3[mt] = MFMA16(ah, X2l[c].v, A3[mt], 0, 0, 0);
            }

        UF X3h[4];
        epi_hi(A3, X3h);

        // ---- L4: plain f16
        f32x4 A4[8];
        initb(A4, 2);
#pragma unroll
        for (int c = 0; c < 4; ++c)
#pragma unroll
            for (int mt = 0; mt < 8; ++mt) {
                f16x8 ah = *(const f16x8*)(L4Hp + (c * 8 + mt) * 1024 + lb);
                A4[mt] = MFMA16(ah, X3h[c].v, A4[mt], 0, 0, 0);
            }

        UF X4h[4];
        epi_hi(A4, X4h);

        // ---- L5: single M-padded tile
        f32x4 a5 = {0.f, 0.f, 0.f, 0.f};
#pragma unroll
        for (int c = 0; c < 4; ++c) {
            f16x8 ah = *(const f16x8*)(L5Hp + c * 1024 + lb);
            a5 = MFMA16(ah, X4h[c].v, a5, 0, 0, 0);
        }

        if (lane < 16) {   // g==0: rows 0..2 = outputs j=0..2 for point n=lane
            size_t o = ((size_t)b * N_ + pt) * 3;
            out[o]     = a5[0] + b5_0;
            out[o + 1] = a5[1] + b5_1;
            out[o + 2] = a5[2] + b5_2;
        }
    }
}

extern "C" void kernel_launch(void* const* d_in, const int* in_sizes, int n_in,
                              void* d_out, int out_size, void* d_ws, size_t ws_size,
                              hipStream_t stream) {
    (void)in_sizes; (void)n_in; (void)out_size; (void)ws_size;
    const float* x = (const float*)d_in[0];
    const float* p = (const float*)d_in[1];
    float* o = (float*)d_out;
    char* ws = (char*)d_ws;   // needs 32 * 136704 = 4,374,528 B

    hipFuncSetAttribute(reinterpret_cast<const void*>(siren_main),
                        hipFuncAttributeMaxDynamicSharedMemorySize, LDSSET);
    siren_prep<<<dim3(102, 32), 64, 0, stream>>>(p, ws);
    siren_main<<<dim3(32, 8), 512, LDSSET, stream>>>(x, p, o, ws);
}

// Round 9
// 277.412 us; speedup vs baseline: 6.4777x; 1.0812x over previous
//
#include <hip/hip_runtime.h>
#include <stdint.h>

// SIREN batched MLP, MI355X/gfx950 — round 9 (= r8 with cvt_pkrtz type fix):
// r7 structure (16x16x32 MFMA, permuted-k zero-shuffle epilogue) + 32 points
// per wave/iter (two M-tiles share every weight ds_read -> LDS traffic halves)
// + cvt_pkrtz packed splits (epilogue VALU -40%). Hi-only packs stay RTE
// (pkrtz RTZ would double X3/X4 repr error). Precision plan unchanged from r7
// (absmax 0.00488): L1 fp32 VALU, L2 3-term hi/lo, L3 2-term, L4/L5 plain.

typedef _Float16 f16x8 __attribute__((ext_vector_type(8)));
typedef __fp16 h16x2 __attribute__((ext_vector_type(2)));   // cvt_pkrtz return type
typedef float f32x4 __attribute__((ext_vector_type(4)));

#define MFMA16 __builtin_amdgcn_mfma_f32_16x16x32_f16

#define B_ 32
#define N_ 32768

// flat param offsets (floats)
#define OFF_W1 0
#define OFF_B1 256
#define OFF_W2 384
#define OFF_B2 16768
#define OFF_W3 16896
#define OFF_B3 33280
#define OFF_W4 33408
#define OFF_B4 49792
#define OFF_W5 49920
#define OFF_B5 50304
#define NPARAM 50307

// ws / LDS image offsets (bytes). A-frag images: [c][mt][lane]*16B.
#define WO_L2H 0
#define WO_W2L 32768
#define WO_L3H 65536
#define WO_L4H 98304
#define WO_L5H 131072      /* 4 KB: single M-tile, rows 3..15 zero */
#define WO_W1X 135168      /* 128 floats, slot-ordered s = c*32 + k_local */
#define WO_W1Y 135680
#define WO_B1S 136192
#define SWS    136704      /* per-batch ws stride; also bytes staged to LDS */
#define LDS_BIAS 136704    /* 3*128 floats */
#define LDSSET 138240

__device__ __forceinline__ float fast_sin30(float v) {
    float t = v * 4.77464829275686f;   // 30 / (2*pi)
    t = t - floorf(t);
    return __builtin_amdgcn_sinf(t);
}

__device__ __forceinline__ uint32_t pack2(_Float16 a, _Float16 b) {
    union { _Float16 h[2]; uint32_t u; } x;
    x.h[0] = a; x.h[1] = b;
    return x.u;
}

// sin -> hi/lo split for a pair, packed via v_cvt_pkrtz_f16_f32 (1 op/pack).
// RTZ on hi is fine here: lo captures the residual exactly to 2^-22.
__device__ __forceinline__ void sin_split_pk(float a0, float a1,
                                             uint32_t& hw, uint32_t& lw) {
    float s0 = fast_sin30(a0), s1 = fast_sin30(a1);
    union { h16x2 v; uint32_t u; } x, y;
    x.v = __builtin_amdgcn_cvt_pkrtz(s0, s1);
    float l0 = s0 - (float)x.v[0], l1 = s1 - (float)x.v[1];
    y.v = __builtin_amdgcn_cvt_pkrtz(l0, l1);
    hw = x.u; lw = y.u;
}

// ---------------------------------------------------------------------------
// Prep (unchanged from r7, verified). 16x16x32 A-frag: lane l holds
// A[m=16mt+(l&15)][k_local=8*(l>>4)+e]; feature f = 16c + 64*(e>=4) + 4g + (e&3).
// ---------------------------------------------------------------------------
__global__ __launch_bounds__(64) void siren_prep(const float* __restrict__ p0,
                                                 char* __restrict__ ws) {
    const int u = blockIdx.x;      // 0..101
    const int b = blockIdx.y;
    const int l = threadIdx.x;
    const float* p = p0 + (size_t)b * NPARAM;
    char* wb = ws + (size_t)b * SWS;

    if (u < 100) {
        int li, c, mt;
        if (u < 96) { li = u >> 5; int r = u & 31; c = r >> 3; mt = r & 7; }
        else        { li = 3; c = u - 96; mt = 0; }
        const int m = l & 15, gA = l >> 4;
        int wOff; size_t dstH; bool lo = false;
        if (li == 0)      { wOff = OFF_W2; dstH = WO_L2H; lo = true; }
        else if (li == 1) { wOff = OFF_W3; dstH = WO_L3H; }
        else if (li == 2) { wOff = OFF_W4; dstH = WO_L4H; }
        else              { wOff = OFF_W5; dstH = WO_L5H; }
        const int j = (li == 3) ? m : (16 * mt + m);
        const int f0 = 16 * c + 4 * gA;

        float v[8];
        if (li == 3 && m >= 3) {
#pragma unroll
            for (int e = 0; e < 8; ++e) v[e] = 0.f;
        } else {
            float4 a  = *(const float4*)(p + wOff + j * 128 + f0);
            float4 bq = *(const float4*)(p + wOff + j * 128 + f0 + 64);
            v[0] = a.x;  v[1] = a.y;  v[2] = a.z;  v[3] = a.w;
            v[4] = bq.x; v[5] = bq.y; v[6] = bq.z; v[7] = bq.w;
        }
        f16x8 hv, lv;
#pragma unroll
        for (int e = 0; e < 8; ++e) {
            _Float16 hh = (_Float16)v[e];
            hv[e] = hh;
            lv[e] = (_Float16)(v[e] - (float)hh);
        }
        size_t idx = (li == 3) ? (size_t)(c * 64 + l) * 16
                               : (size_t)((c * 8 + mt) * 64 + l) * 16;
        *(f16x8*)(wb + dstH + idx) = hv;
        if (lo) *(f16x8*)(wb + WO_W2L + idx) = lv;
    } else {
        int s = (u - 100) * 64 + l;            // 0..127
        int c = s >> 5, k = s & 31, gq = k >> 3, e = k & 7;
        int f = 16 * c + ((e & 4) ? 64 : 0) + 4 * gq + (e & 3);
        ((float*)(wb + WO_W1X))[s] = p[OFF_W1 + 2 * f];
        ((float*)(wb + WO_W1Y))[s] = p[OFF_W1 + 2 * f + 1];
        ((float*)(wb + WO_B1S))[s] = p[OFF_B1 + f];
    }
}

// ---------------------------------------------------------------------------
// Main: 512 threads = 8 waves, 1 block/CU (135 KB LDS). Wave does 32 points
// (two 16-pt M-tiles) per iter, 16 iters. Grid (32 batches, 8 slabs).
// ---------------------------------------------------------------------------
__global__ __launch_bounds__(512, 2)
void siren_main(const float* __restrict__ xg,
                const float* __restrict__ pg,
                float* __restrict__ out,
                const char* __restrict__ ws) {
    extern __shared__ __align__(16) char smem[];

    const int t = threadIdx.x;
    const int b = blockIdx.x;
    const int grp = blockIdx.y;
    const char* wb = ws + (size_t)b * SWS;
    const float* p = pg + (size_t)b * NPARAM;

    {
        const float4* src = (const float4*)wb;
        float4* dst = (float4*)smem;
        for (int i = t; i < SWS / 16; i += 512) dst[i] = src[i];
    }
    float* sB = (float*)(smem + LDS_BIAS);
    if (t < 384) {
        int li = t >> 7, f = t & 127;
        sB[t] = p[(li == 0 ? OFF_B2 : li == 1 ? OFF_B3 : OFF_B4) + f];
    }
    const float b5_0 = p[OFF_B5], b5_1 = p[OFF_B5 + 1], b5_2 = p[OFF_B5 + 2];
    __syncthreads();

    const int lane = t & 63;
    const int wv = t >> 6;
    const int n = lane & 15;
    const int g = lane >> 4;
    const int lb = lane * 16;

    const char* L2Hp = smem + WO_L2H;
    const char* W2Lp = smem + WO_W2L;
    const char* L3Hp = smem + WO_L3H;
    const char* L4Hp = smem + WO_L4H;
    const char* L5Hp = smem + WO_L5H;
    const float* W1X = (const float*)(smem + WO_W1X);
    const float* W1Y = (const float*)(smem + WO_W1Y);
    const float* B1S = (const float*)(smem + WO_B1S);

    union UF { f16x8 v; uint32_t w[4]; };

    auto initb2 = [&](f32x4 (&A)[2][8], int li) {
#pragma unroll
        for (int mt = 0; mt < 8; ++mt) {
            f32x4 bb = *(const f32x4*)&sB[li * 128 + 16 * mt + 4 * g];
            A[0][mt] = bb;
            A[1][mt] = bb;
        }
    };

    // acc -> B-frag chunk c = {tile c regs 0-3 (e0-3), tile c+4 regs 0-3 (e4-7)}
    auto epi_split2 = [&](const f32x4 (&A)[2][8], UF (&Xh)[2][4], UF (&Xl)[2][4]) {
#pragma unroll
        for (int pp = 0; pp < 2; ++pp)
#pragma unroll
            for (int c = 0; c < 4; ++c) {
                sin_split_pk(A[pp][c][0],     A[pp][c][1],     Xh[pp][c].w[0], Xl[pp][c].w[0]);
                sin_split_pk(A[pp][c][2],     A[pp][c][3],     Xh[pp][c].w[1], Xl[pp][c].w[1]);
                sin_split_pk(A[pp][c + 4][0], A[pp][c + 4][1], Xh[pp][c].w[2], Xl[pp][c].w[2]);
                sin_split_pk(A[pp][c + 4][2], A[pp][c + 4][3], Xh[pp][c].w[3], Xl[pp][c].w[3]);
            }
    };

    // hi-only epilogue keeps RTE converts (RTZ would double X3/X4 repr error)
    auto epi_hi2 = [&](const f32x4 (&A)[2][8], UF (&Xh)[2][4]) {
#pragma unroll
        for (int pp = 0; pp < 2; ++pp)
#pragma unroll
            for (int c = 0; c < 4; ++c) {
                _Float16 hh[8];
#pragma unroll
                for (int r = 0; r < 4; ++r) {
                    hh[r]     = (_Float16)fast_sin30(A[pp][c][r]);
                    hh[4 + r] = (_Float16)fast_sin30(A[pp][c + 4][r]);
                }
                Xh[pp][c].w[0] = pack2(hh[0], hh[1]); Xh[pp][c].w[1] = pack2(hh[2], hh[3]);
                Xh[pp][c].w[2] = pack2(hh[4], hh[5]); Xh[pp][c].w[3] = pack2(hh[6], hh[7]);
            }
    };

#pragma unroll 1
    for (int iter = 0; iter < 16; ++iter) {
        asm volatile("" ::: "memory");   // block cross-iter LDS-load hoisting

        const int ptb = grp * 4096 + iter * 256 + wv * 32;
        const float2 xy0 = ((const float2*)xg)[(size_t)b * N_ + ptb + n];
        const float2 xy1 = ((const float2*)xg)[(size_t)b * N_ + ptb + 16 + n];

        // ---- L1: fp32 VALU straight into B-frag slots (both point-tiles)
        UF X1h[2][4], X1l[2][4];
#pragma unroll
        for (int c = 0; c < 4; ++c) {
            const int s0 = c * 32 + g * 8;
            float4 wxa = *(const float4*)(W1X + s0), wxb = *(const float4*)(W1X + s0 + 4);
            float4 wya = *(const float4*)(W1Y + s0), wyb = *(const float4*)(W1Y + s0 + 4);
            float4 bba = *(const float4*)(B1S + s0), bbb = *(const float4*)(B1S + s0 + 4);
            float wx[8] = {wxa.x, wxa.y, wxa.z, wxa.w, wxb.x, wxb.y, wxb.z, wxb.w};
            float wy[8] = {wya.x, wya.y, wya.z, wya.w, wyb.x, wyb.y, wyb.z, wyb.w};
            float bc[8] = {bba.x, bba.y, bba.z, bba.w, bbb.x, bbb.y, bbb.z, bbb.w};
#pragma unroll
            for (int pp = 0; pp < 2; ++pp) {
                const float px = pp ? xy1.x : xy0.x;
                const float py = pp ? xy1.y : xy0.y;
                float a[8];
#pragma unroll
                for (int e = 0; e < 8; ++e)
                    a[e] = fmaf(px, wx[e], fmaf(py, wy[e], bc[e]));
                sin_split_pk(a[0], a[1], X1h[pp][c].w[0], X1l[pp][c].w[0]);
                sin_split_pk(a[2], a[3], X1h[pp][c].w[1], X1l[pp][c].w[1]);
                sin_split_pk(a[4], a[5], X1h[pp][c].w[2], X1l[pp][c].w[2]);
                sin_split_pk(a[6], a[7], X1h[pp][c].w[3], X1l[pp][c].w[3]);
            }
        }

        // ---- L2: 3-term hi/lo split; weight frags read once, used 6x
        f32x4 A2[2][8];
        initb2(A2, 0);
#pragma unroll
        for (int c = 0; c < 4; ++c)
#pragma unroll
            for (int mt = 0; mt < 8; ++mt) {
                f16x8 ah = *(const f16x8*)(L2Hp + (c * 8 + mt) * 1024 + lb);
                f16x8 al = *(const f16x8*)(W2Lp + (c * 8 + mt) * 1024 + lb);
#pragma unroll
                for (int pp = 0; pp < 2; ++pp) {
                    A2[pp][mt] = MFMA16(ah, X1h[pp][c].v, A2[pp][mt], 0, 0, 0);
                    A2[pp][mt] = MFMA16(ah, X1l[pp][c].v, A2[pp][mt], 0, 0, 0);
                    A2[pp][mt] = MFMA16(al, X1h[pp][c].v, A2[pp][mt], 0, 0, 0);
                }
            }

        UF X2h[2][4], X2l[2][4];
        epi_split2(A2, X2h, X2l);

        // ---- L3: 2-term
        f32x4 A3[2][8];
        initb2(A3, 1);
#pragma unroll
        for (int c = 0; c < 4; ++c)
#pragma unroll
            for (int mt = 0; mt < 8; ++mt) {
                f16x8 ah = *(const f16x8*)(L3Hp + (c * 8 + mt) * 1024 + lb);
#pragma unroll
                for (int pp = 0; pp < 2; ++pp) {
                    A3[pp][mt] = MFMA16(ah, X2h[pp][c].v, A3[pp][mt], 0, 0, 0);
                    A3[pp][mt] = MFMA16(ah, X2l[pp][c].v, A3[pp][mt], 0, 0, 0);
                }
            }

        UF X3h[2][4];
        epi_hi2(A3, X3h);

        // ---- L4: plain f16
        f32x4 A4[2][8];
        initb2(A4, 2);
#pragma unroll
        for (int c = 0; c < 4; ++c)
#pragma unroll
            for (int mt = 0; mt < 8; ++mt) {
                f16x8 ah = *(const f16x8*)(L4Hp + (c * 8 + mt) * 1024 + lb);
#pragma unroll
                for (int pp = 0; pp < 2; ++pp)
                    A4[pp][mt] = MFMA16(ah, X3h[pp][c].v, A4[pp][mt], 0, 0, 0);
            }

        UF X4h[2][4];
        epi_hi2(A4, X4h);

        // ---- L5: single M-padded tile per point-tile
        f32x4 a5[2] = {{0.f, 0.f, 0.f, 0.f}, {0.f, 0.f, 0.f, 0.f}};
#pragma unroll
        for (int c = 0; c < 4; ++c) {
            f16x8 ah = *(const f16x8*)(L5Hp + c * 1024 + lb);
#pragma unroll
            for (int pp = 0; pp < 2; ++pp)
                a5[pp] = MFMA16(ah, X4h[pp][c].v, a5[pp], 0, 0, 0);
        }

        if (g == 0) {   // rows 0..2 = outputs j=0..2 for point n
#pragma unroll
            for (int pp = 0; pp < 2; ++pp) {
                size_t o = ((size_t)b * N_ + ptb + pp * 16 + n) * 3;
                out[o]     = a5[pp][0] + b5_0;
                out[o + 1] = a5[pp][1] + b5_1;
                out[o + 2] = a5[pp][2] + b5_2;
            }
        }
    }
}

extern "C" void kernel_launch(void* const* d_in, const int* in_sizes, int n_in,
                              void* d_out, int out_size, void* d_ws, size_t ws_size,
                              hipStream_t stream) {
    (void)in_sizes; (void)n_in; (void)out_size; (void)ws_size;
    const float* x = (const float*)d_in[0];
    const float* p = (const float*)d_in[1];
    float* o = (float*)d_out;
    char* ws = (char*)d_ws;   // needs 32 * 136704 = 4,374,528 B

    (void)hipFuncSetAttribute(reinterpret_cast<const void*>(siren_main),
                              hipFuncAttributeMaxDynamicSharedMemorySize, LDSSET);
    siren_prep<<<dim3(102, 32), 64, 0, stream>>>(p, ws);
    siren_main<<<dim3(32, 8), 512, LDSSET, stream>>>(x, p, o, ws);
}

// Round 11
// 238.475 us; speedup vs baseline: 7.5354x; 1.1633x over previous
//
#include <hip/hip_runtime.h>
#include <stdint.h>

// SIREN batched MLP, MI355X/gfx950 — round 11: r9 config + ONE precision cut.
// r10 lesson: {W2-lo drop, X2-lo drop, RTZ hi-epilogues} = +0.0171 absmax
// (RTZ bias is sign-correlated with activations -> semi-coherent injection;
// W2-lo sits one 4.8x gain layer above W3-lo). r11 keeps:
//   - L2 3-term (W2 hi/lo),  L3 1-term (X2-lo DROPPED, ~+0.0015),
//   - L4/L5 plain, RTE packs in all hi-only epilogues,
//   - pkrtz only in X1 split (lo captures RTZ residual exactly),
//   - v_fract sine (exact, -1 op/sine).
// MFMA/wave-iter 392 -> 328. Predicted absmax ~0.007, kernel ~215 us.

typedef _Float16 f16x8 __attribute__((ext_vector_type(8)));
typedef __fp16 h16x2 __attribute__((ext_vector_type(2)));   // cvt_pkrtz return type
typedef float f32x4 __attribute__((ext_vector_type(4)));

#define MFMA16 __builtin_amdgcn_mfma_f32_16x16x32_f16

#define B_ 32
#define N_ 32768

// flat param offsets (floats)
#define OFF_W1 0
#define OFF_B1 256
#define OFF_W2 384
#define OFF_B2 16768
#define OFF_W3 16896
#define OFF_B3 33280
#define OFF_W4 33408
#define OFF_B4 49792
#define OFF_W5 49920
#define OFF_B5 50304
#define NPARAM 50307

// ws / LDS image offsets (bytes). A-frag images: [c][mt][lane]*16B.
#define WO_L2H 0
#define WO_W2L 32768
#define WO_L3H 65536
#define WO_L4H 98304
#define WO_L5H 131072      /* 4 KB: single M-tile, rows 3..15 zero */
#define WO_W1X 135168      /* 128 floats, slot-ordered s = c*32 + k_local */
#define WO_W1Y 135680
#define WO_B1S 136192
#define SWS    136704      /* per-batch ws stride; also bytes staged to LDS */
#define LDS_BIAS 136704    /* 3*128 floats */
#define LDSSET 138240

__device__ __forceinline__ float fast_sin30(float v) {
    float t = v * 4.77464829275686f;            // 30 / (2*pi)
    t = __builtin_amdgcn_fractf(t);             // v_fract_f32 (one op)
    return __builtin_amdgcn_sinf(t);
}

__device__ __forceinline__ uint32_t pack2(_Float16 a, _Float16 b) {
    union { _Float16 h[2]; uint32_t u; } x;
    x.h[0] = a; x.h[1] = b;
    return x.u;
}

// sin pair -> hi/lo split packed via pkrtz (lo captures RTZ residual exactly)
__device__ __forceinline__ void sin_split_pk(float a0, float a1,
                                             uint32_t& hw, uint32_t& lw) {
    float s0 = fast_sin30(a0), s1 = fast_sin30(a1);
    union { h16x2 v; uint32_t u; } x, y;
    x.v = __builtin_amdgcn_cvt_pkrtz(s0, s1);
    float l0 = s0 - (float)x.v[0], l1 = s1 - (float)x.v[1];
    y.v = __builtin_amdgcn_cvt_pkrtz(l0, l1);
    hw = x.u; lw = y.u;
}

// ---------------------------------------------------------------------------
// Prep (r7-verified layout). 16x16x32 A-frag: lane l holds
// A[m=16mt+(l&15)][k_local=8*(l>>4)+e]; feature f = 16c + 64*(e>=4) + 4g + (e&3).
// W2 stored hi+lo; W3/W4/W5 hi only.
// ---------------------------------------------------------------------------
__global__ __launch_bounds__(64) void siren_prep(const float* __restrict__ p0,
                                                 char* __restrict__ ws) {
    const int u = blockIdx.x;      // 0..101
    const int b = blockIdx.y;
    const int l = threadIdx.x;
    const float* p = p0 + (size_t)b * NPARAM;
    char* wb = ws + (size_t)b * SWS;

    if (u < 100) {
        int li, c, mt;
        if (u < 96) { li = u >> 5; int r = u & 31; c = r >> 3; mt = r & 7; }
        else        { li = 3; c = u - 96; mt = 0; }
        const int m = l & 15, gA = l >> 4;
        int wOff; size_t dstH; bool lo = false;
        if (li == 0)      { wOff = OFF_W2; dstH = WO_L2H; lo = true; }
        else if (li == 1) { wOff = OFF_W3; dstH = WO_L3H; }
        else if (li == 2) { wOff = OFF_W4; dstH = WO_L4H; }
        else              { wOff = OFF_W5; dstH = WO_L5H; }
        const int j = (li == 3) ? m : (16 * mt + m);
        const int f0 = 16 * c + 4 * gA;

        float v[8];
        if (li == 3 && m >= 3) {
#pragma unroll
            for (int e = 0; e < 8; ++e) v[e] = 0.f;
        } else {
            float4 a  = *(const float4*)(p + wOff + j * 128 + f0);
            float4 bq = *(const float4*)(p + wOff + j * 128 + f0 + 64);
            v[0] = a.x;  v[1] = a.y;  v[2] = a.z;  v[3] = a.w;
            v[4] = bq.x; v[5] = bq.y; v[6] = bq.z; v[7] = bq.w;
        }
        f16x8 hv, lv;
#pragma unroll
        for (int e = 0; e < 8; ++e) {
            _Float16 hh = (_Float16)v[e];
            hv[e] = hh;
            lv[e] = (_Float16)(v[e] - (float)hh);
        }
        size_t idx = (li == 3) ? (size_t)(c * 64 + l) * 16
                               : (size_t)((c * 8 + mt) * 64 + l) * 16;
        *(f16x8*)(wb + dstH + idx) = hv;
        if (lo) *(f16x8*)(wb + WO_W2L + idx) = lv;
    } else {
        int s = (u - 100) * 64 + l;            // 0..127
        int c = s >> 5, k = s & 31, gq = k >> 3, e = k & 7;
        int f = 16 * c + ((e & 4) ? 64 : 0) + 4 * gq + (e & 3);
        ((float*)(wb + WO_W1X))[s] = p[OFF_W1 + 2 * f];
        ((float*)(wb + WO_W1Y))[s] = p[OFF_W1 + 2 * f + 1];
        ((float*)(wb + WO_B1S))[s] = p[OFF_B1 + f];
    }
}

// ---------------------------------------------------------------------------
// Main: 512 threads = 8 waves, 1 block/CU (135 KB LDS). Wave does 32 points
// (two 16-pt M-tiles) per iter, 16 iters. Grid (32 batches, 8 slabs).
// ---------------------------------------------------------------------------
__global__ __launch_bounds__(512, 2)
void siren_main(const float* __restrict__ xg,
                const float* __restrict__ pg,
                float* __restrict__ out,
                const char* __restrict__ ws) {
    extern __shared__ __align__(16) char smem[];

    const int t = threadIdx.x;
    const int b = blockIdx.x;
    const int grp = blockIdx.y;
    const char* wb = ws + (size_t)b * SWS;
    const float* p = pg + (size_t)b * NPARAM;

    {
        const float4* src = (const float4*)wb;
        float4* dst = (float4*)smem;
        for (int i = t; i < SWS / 16; i += 512) dst[i] = src[i];
    }
    float* sB = (float*)(smem + LDS_BIAS);
    if (t < 384) {
        int li = t >> 7, f = t & 127;
        sB[t] = p[(li == 0 ? OFF_B2 : li == 1 ? OFF_B3 : OFF_B4) + f];
    }
    const float b5_0 = p[OFF_B5], b5_1 = p[OFF_B5 + 1], b5_2 = p[OFF_B5 + 2];
    __syncthreads();

    const int lane = t & 63;
    const int wv = t >> 6;
    const int n = lane & 15;
    const int g = lane >> 4;
    const int lb = lane * 16;

    const char* L2Hp = smem + WO_L2H;
    const char* W2Lp = smem + WO_W2L;
    const char* L3Hp = smem + WO_L3H;
    const char* L4Hp = smem + WO_L4H;
    const char* L5Hp = smem + WO_L5H;
    const float* W1X = (const float*)(smem + WO_W1X);
    const float* W1Y = (const float*)(smem + WO_W1Y);
    const float* B1S = (const float*)(smem + WO_B1S);

    union UF { f16x8 v; uint32_t w[4]; };

    auto initb2 = [&](f32x4 (&A)[2][8], int li) {
#pragma unroll
        for (int mt = 0; mt < 8; ++mt) {
            f32x4 bb = *(const f32x4*)&sB[li * 128 + 16 * mt + 4 * g];
            A[0][mt] = bb;
            A[1][mt] = bb;
        }
    };

    // acc -> B-frag chunk c = {tile c regs 0-3 (e0-3), tile c+4 regs 0-3 (e4-7)}
    // RTE converts (hi-only: RTZ bias would inject sign-correlated error)
    auto epi_hi2 = [&](const f32x4 (&A)[2][8], UF (&Xh)[2][4]) {
#pragma unroll
        for (int pp = 0; pp < 2; ++pp)
#pragma unroll
            for (int c = 0; c < 4; ++c) {
                _Float16 hh[8];
#pragma unroll
                for (int r = 0; r < 4; ++r) {
                    hh[r]     = (_Float16)fast_sin30(A[pp][c][r]);
                    hh[4 + r] = (_Float16)fast_sin30(A[pp][c + 4][r]);
                }
                Xh[pp][c].w[0] = pack2(hh[0], hh[1]); Xh[pp][c].w[1] = pack2(hh[2], hh[3]);
                Xh[pp][c].w[2] = pack2(hh[4], hh[5]); Xh[pp][c].w[3] = pack2(hh[6], hh[7]);
            }
    };

#pragma unroll 1
    for (int iter = 0; iter < 16; ++iter) {
        asm volatile("" ::: "memory");   // block cross-iter LDS-load hoisting

        const int ptb = grp * 4096 + iter * 256 + wv * 32;
        const float2 xy0 = ((const float2*)xg)[(size_t)b * N_ + ptb + n];
        const float2 xy1 = ((const float2*)xg)[(size_t)b * N_ + ptb + 16 + n];

        // ---- L1: fp32 VALU straight into B-frag slots (both point-tiles)
        UF X1h[2][4], X1l[2][4];
#pragma unroll
        for (int c = 0; c < 4; ++c) {
            const int s0 = c * 32 + g * 8;
            float4 wxa = *(const float4*)(W1X + s0), wxb = *(const float4*)(W1X + s0 + 4);
            float4 wya = *(const float4*)(W1Y + s0), wyb = *(const float4*)(W1Y + s0 + 4);
            float4 bba = *(const float4*)(B1S + s0), bbb = *(const float4*)(B1S + s0 + 4);
            float wx[8] = {wxa.x, wxa.y, wxa.z, wxa.w, wxb.x, wxb.y, wxb.z, wxb.w};
            float wy[8] = {wya.x, wya.y, wya.z, wya.w, wyb.x, wyb.y, wyb.z, wyb.w};
            float bc[8] = {bba.x, bba.y, bba.z, bba.w, bbb.x, bbb.y, bbb.z, bbb.w};
#pragma unroll
            for (int pp = 0; pp < 2; ++pp) {
                const float px = pp ? xy1.x : xy0.x;
                const float py = pp ? xy1.y : xy0.y;
                float a[8];
#pragma unroll
                for (int e = 0; e < 8; ++e)
                    a[e] = fmaf(px, wx[e], fmaf(py, wy[e], bc[e]));
                sin_split_pk(a[0], a[1], X1h[pp][c].w[0], X1l[pp][c].w[0]);
                sin_split_pk(a[2], a[3], X1h[pp][c].w[1], X1l[pp][c].w[1]);
                sin_split_pk(a[4], a[5], X1h[pp][c].w[2], X1l[pp][c].w[2]);
                sin_split_pk(a[6], a[7], X1h[pp][c].w[3], X1l[pp][c].w[3]);
            }
        }

        // ---- L2: 3-term hi/lo split; weight frags read once, used 6x
        f32x4 A2[2][8];
        initb2(A2, 0);
#pragma unroll
        for (int c = 0; c < 4; ++c)
#pragma unroll
            for (int mt = 0; mt < 8; ++mt) {
                f16x8 ah = *(const f16x8*)(L2Hp + (c * 8 + mt) * 1024 + lb);
                f16x8 al = *(const f16x8*)(W2Lp + (c * 8 + mt) * 1024 + lb);
#pragma unroll
                for (int pp = 0; pp < 2; ++pp) {
                    A2[pp][mt] = MFMA16(ah, X1h[pp][c].v, A2[pp][mt], 0, 0, 0);
                    A2[pp][mt] = MFMA16(ah, X1l[pp][c].v, A2[pp][mt], 0, 0, 0);
                    A2[pp][mt] = MFMA16(al, X1h[pp][c].v, A2[pp][mt], 0, 0, 0);
                }
            }

        UF X2h[2][4];
        epi_hi2(A2, X2h);

        // ---- L3: 1-term (X2 hi only; RTE-packed above)
        f32x4 A3[2][8];
        initb2(A3, 1);
#pragma unroll
        for (int c = 0; c < 4; ++c)
#pragma unroll
            for (int mt = 0; mt < 8; ++mt) {
                f16x8 ah = *(const f16x8*)(L3Hp + (c * 8 + mt) * 1024 + lb);
#pragma unroll
                for (int pp = 0; pp < 2; ++pp)
                    A3[pp][mt] = MFMA16(ah, X2h[pp][c].v, A3[pp][mt], 0, 0, 0);
            }

        UF X3h[2][4];
        epi_hi2(A3, X3h);

        // ---- L4: plain f16
        f32x4 A4[2][8];
        initb2(A4, 2);
#pragma unroll
        for (int c = 0; c < 4; ++c)
#pragma unroll
            for (int mt = 0; mt < 8; ++mt) {
                f16x8 ah = *(const f16x8*)(L4Hp + (c * 8 + mt) * 1024 + lb);
#pragma unroll
                for (int pp = 0; pp < 2; ++pp)
                    A4[pp][mt] = MFMA16(ah, X3h[pp][c].v, A4[pp][mt], 0, 0, 0);
            }

        UF X4h[2][4];
        epi_hi2(A4, X4h);

        // ---- L5: single M-padded tile per point-tile
        f32x4 a5[2] = {{0.f, 0.f, 0.f, 0.f}, {0.f, 0.f, 0.f, 0.f}};
#pragma unroll
        for (int c = 0; c < 4; ++c) {
            f16x8 ah = *(const f16x8*)(L5Hp + c * 1024 + lb);
#pragma unroll
            for (int pp = 0; pp < 2; ++pp)
                a5[pp] = MFMA16(ah, X4h[pp][c].v, a5[pp], 0, 0, 0);
        }

        if (g == 0) {   // rows 0..2 = outputs j=0..2 for point n
#pragma unroll
            for (int pp = 0; pp < 2; ++pp) {
                size_t o = ((size_t)b * N_ + ptb + pp * 16 + n) * 3;
                out[o]     = a5[pp][0] + b5_0;
                out[o + 1] = a5[pp][1] + b5_1;
                out[o + 2] = a5[pp][2] + b5_2;
            }
        }
    }
}

extern "C" void kernel_launch(void* const* d_in, const int* in_sizes, int n_in,
                              void* d_out, int out_size, void* d_ws, size_t ws_size,
                              hipStream_t stream) {
    (void)in_sizes; (void)n_in; (void)out_size; (void)ws_size;
    const float* x = (const float*)d_in[0];
    const float* p = (const float*)d_in[1];
    float* o = (float*)d_out;
    char* ws = (char*)d_ws;   // needs 32 * 136704 = 4,374,528 B

    (void)hipFuncSetAttribute(reinterpret_cast<const void*>(siren_main),
                              hipFuncAttributeMaxDynamicSharedMemorySize, LDSSET);
    siren_prep<<<dim3(102, 32), 64, 0, stream>>>(p, ws);
    siren_main<<<dim3(32, 8), 512, LDSSET, stream>>>(x, p, o, ws);
}

// Round 12
// 231.661 us; speedup vs baseline: 7.7570x; 1.0294x over previous
//
#include <hip/hip_runtime.h>
#include <stdint.h>

// SIREN batched MLP, MI355X/gfx950 — round 12: r11 numerics, 3 waves/SIMD.
// r11 finding: VALU(117us) + MFMA(77us) add up serially (sum=96%) because a
// wave's chain is mfma->epi->mfma and 2 waves/SIMD (LDS-capped) can't
// anti-phase the two pipes (m114: they CAN run concurrently). Fix: ONE
// 768-thread block per CU (12 waves = 3/SIMD, LDS 135K still fits,
// 3x170=510<=512 reg pool via __launch_bounds__(768,3)).
// Numerics unchanged from r11 (absmax 0.00684): L1 fp32+split, L2 3-term,
// L3/L4/L5 hi-only RTE, v_fract sine, pkrtz only where lo captures residual.

typedef _Float16 f16x8 __attribute__((ext_vector_type(8)));
typedef __fp16 h16x2 __attribute__((ext_vector_type(2)));   // cvt_pkrtz return type
typedef float f32x4 __attribute__((ext_vector_type(4)));

#define MFMA16 __builtin_amdgcn_mfma_f32_16x16x32_f16

#define B_ 32
#define N_ 32768
#define NTHR 768
#define NWAVE 12

// flat param offsets (floats)
#define OFF_W1 0
#define OFF_B1 256
#define OFF_W2 384
#define OFF_B2 16768
#define OFF_W3 16896
#define OFF_B3 33280
#define OFF_W4 33408
#define OFF_B4 49792
#define OFF_W5 49920
#define OFF_B5 50304
#define NPARAM 50307

// ws / LDS image offsets (bytes). A-frag images: [c][mt][lane]*16B.
#define WO_L2H 0
#define WO_W2L 32768
#define WO_L3H 65536
#define WO_L4H 98304
#define WO_L5H 131072      /* 4 KB: single M-tile, rows 3..15 zero */
#define WO_W1X 135168      /* 128 floats, slot-ordered s = c*32 + k_local */
#define WO_W1Y 135680
#define WO_B1S 136192
#define SWS    136704      /* per-batch ws stride; also bytes staged to LDS */
#define LDS_BIAS 136704    /* 3*128 floats */
#define LDSSET 138240

__device__ __forceinline__ float fast_sin30(float v) {
    float t = v * 4.77464829275686f;            // 30 / (2*pi)
    t = __builtin_amdgcn_fractf(t);             // v_fract_f32 (one op)
    return __builtin_amdgcn_sinf(t);
}

__device__ __forceinline__ uint32_t pack2(_Float16 a, _Float16 b) {
    union { _Float16 h[2]; uint32_t u; } x;
    x.h[0] = a; x.h[1] = b;
    return x.u;
}

// sin pair -> hi/lo split packed via pkrtz (lo captures RTZ residual exactly)
__device__ __forceinline__ void sin_split_pk(float a0, float a1,
                                             uint32_t& hw, uint32_t& lw) {
    float s0 = fast_sin30(a0), s1 = fast_sin30(a1);
    union { h16x2 v; uint32_t u; } x, y;
    x.v = __builtin_amdgcn_cvt_pkrtz(s0, s1);
    float l0 = s0 - (float)x.v[0], l1 = s1 - (float)x.v[1];
    y.v = __builtin_amdgcn_cvt_pkrtz(l0, l1);
    hw = x.u; lw = y.u;
}

// ---------------------------------------------------------------------------
// Prep (r7-verified layout). 16x16x32 A-frag: lane l holds
// A[m=16mt+(l&15)][k_local=8*(l>>4)+e]; feature f = 16c + 64*(e>=4) + 4g + (e&3).
// W2 stored hi+lo; W3/W4/W5 hi only.
// ---------------------------------------------------------------------------
__global__ __launch_bounds__(64) void siren_prep(const float* __restrict__ p0,
                                                 char* __restrict__ ws) {
    const int u = blockIdx.x;      // 0..101
    const int b = blockIdx.y;
    const int l = threadIdx.x;
    const float* p = p0 + (size_t)b * NPARAM;
    char* wb = ws + (size_t)b * SWS;

    if (u < 100) {
        int li, c, mt;
        if (u < 96) { li = u >> 5; int r = u & 31; c = r >> 3; mt = r & 7; }
        else        { li = 3; c = u - 96; mt = 0; }
        const int m = l & 15, gA = l >> 4;
        int wOff; size_t dstH; bool lo = false;
        if (li == 0)      { wOff = OFF_W2; dstH = WO_L2H; lo = true; }
        else if (li == 1) { wOff = OFF_W3; dstH = WO_L3H; }
        else if (li == 2) { wOff = OFF_W4; dstH = WO_L4H; }
        else              { wOff = OFF_W5; dstH = WO_L5H; }
        const int j = (li == 3) ? m : (16 * mt + m);
        const int f0 = 16 * c + 4 * gA;

        float v[8];
        if (li == 3 && m >= 3) {
#pragma unroll
            for (int e = 0; e < 8; ++e) v[e] = 0.f;
        } else {
            float4 a  = *(const float4*)(p + wOff + j * 128 + f0);
            float4 bq = *(const float4*)(p + wOff + j * 128 + f0 + 64);
            v[0] = a.x;  v[1] = a.y;  v[2] = a.z;  v[3] = a.w;
            v[4] = bq.x; v[5] = bq.y; v[6] = bq.z; v[7] = bq.w;
        }
        f16x8 hv, lv;
#pragma unroll
        for (int e = 0; e < 8; ++e) {
            _Float16 hh = (_Float16)v[e];
            hv[e] = hh;
            lv[e] = (_Float16)(v[e] - (float)hh);
        }
        size_t idx = (li == 3) ? (size_t)(c * 64 + l) * 16
                               : (size_t)((c * 8 + mt) * 64 + l) * 16;
        *(f16x8*)(wb + dstH + idx) = hv;
        if (lo) *(f16x8*)(wb + WO_W2L + idx) = lv;
    } else {
        int s = (u - 100) * 64 + l;            // 0..127
        int c = s >> 5, k = s & 31, gq = k >> 3, e = k & 7;
        int f = 16 * c + ((e & 4) ? 64 : 0) + 4 * gq + (e & 3);
        ((float*)(wb + WO_W1X))[s] = p[OFF_W1 + 2 * f];
        ((float*)(wb + WO_W1Y))[s] = p[OFF_W1 + 2 * f + 1];
        ((float*)(wb + WO_B1S))[s] = p[OFF_B1 + f];
    }
}

// ---------------------------------------------------------------------------
// Main: 768 threads = 12 waves = 3 waves/SIMD, 1 block/CU (135 KB LDS).
// Block covers a 4096-pt slab = 128 32-pt tiles; wave w takes tiles
// w, w+12, ... (8 waves x 11 + 4 waves x 10). Grid (32 batches, 8 slabs).
// ---------------------------------------------------------------------------
__global__ __launch_bounds__(NTHR, 3)
void siren_main(const float* __restrict__ xg,
                const float* __restrict__ pg,
                float* __restrict__ out,
                const char* __restrict__ ws) {
    extern __shared__ __align__(16) char smem[];

    const int t = threadIdx.x;
    const int b = blockIdx.x;
    const int grp = blockIdx.y;
    const char* wb = ws + (size_t)b * SWS;
    const float* p = pg + (size_t)b * NPARAM;

    {
        const float4* src = (const float4*)wb;
        float4* dst = (float4*)smem;
        for (int i = t; i < SWS / 16; i += NTHR) dst[i] = src[i];
    }
    float* sB = (float*)(smem + LDS_BIAS);
    if (t < 384) {
        int li = t >> 7, f = t & 127;
        sB[t] = p[(li == 0 ? OFF_B2 : li == 1 ? OFF_B3 : OFF_B4) + f];
    }
    const float b5_0 = p[OFF_B5], b5_1 = p[OFF_B5 + 1], b5_2 = p[OFF_B5 + 2];
    __syncthreads();

    const int lane = t & 63;
    const int wv = t >> 6;          // 0..11
    const int n = lane & 15;
    const int g = lane >> 4;
    const int lb = lane * 16;

    const char* L2Hp = smem + WO_L2H;
    const char* W2Lp = smem + WO_W2L;
    const char* L3Hp = smem + WO_L3H;
    const char* L4Hp = smem + WO_L4H;
    const char* L5Hp = smem + WO_L5H;
    const float* W1X = (const float*)(smem + WO_W1X);
    const float* W1Y = (const float*)(smem + WO_W1Y);
    const float* B1S = (const float*)(smem + WO_B1S);

    union UF { f16x8 v; uint32_t w[4]; };

    auto initb2 = [&](f32x4 (&A)[2][8], int li) {
#pragma unroll
        for (int mt = 0; mt < 8; ++mt) {
            f32x4 bb = *(const f32x4*)&sB[li * 128 + 16 * mt + 4 * g];
            A[0][mt] = bb;
            A[1][mt] = bb;
        }
    };

    // acc -> B-frag chunk c = {tile c regs 0-3 (e0-3), tile c+4 regs 0-3 (e4-7)}
    // RTE converts (hi-only: RTZ bias would inject sign-correlated error)
    auto epi_hi2 = [&](const f32x4 (&A)[2][8], UF (&Xh)[2][4]) {
#pragma unroll
        for (int pp = 0; pp < 2; ++pp)
#pragma unroll
            for (int c = 0; c < 4; ++c) {
                _Float16 hh[8];
#pragma unroll
                for (int r = 0; r < 4; ++r) {
                    hh[r]     = (_Float16)fast_sin30(A[pp][c][r]);
                    hh[4 + r] = (_Float16)fast_sin30(A[pp][c + 4][r]);
                }
                Xh[pp][c].w[0] = pack2(hh[0], hh[1]); Xh[pp][c].w[1] = pack2(hh[2], hh[3]);
                Xh[pp][c].w[2] = pack2(hh[4], hh[5]); Xh[pp][c].w[3] = pack2(hh[6], hh[7]);
            }
    };

#pragma unroll 1
    for (int tile = wv; tile < 128; tile += NWAVE) {
        asm volatile("" ::: "memory");   // block cross-iter LDS-load hoisting

        const int ptb = grp * 4096 + tile * 32;
        const float2 xy0 = ((const float2*)xg)[(size_t)b * N_ + ptb + n];
        const float2 xy1 = ((const float2*)xg)[(size_t)b * N_ + ptb + 16 + n];

        // ---- L1: fp32 VALU straight into B-frag slots (both point-tiles)
        UF X1h[2][4], X1l[2][4];
#pragma unroll
        for (int c = 0; c < 4; ++c) {
            const int s0 = c * 32 + g * 8;
            float4 wxa = *(const float4*)(W1X + s0), wxb = *(const float4*)(W1X + s0 + 4);
            float4 wya = *(const float4*)(W1Y + s0), wyb = *(const float4*)(W1Y + s0 + 4);
            float4 bba = *(const float4*)(B1S + s0), bbb = *(const float4*)(B1S + s0 + 4);
            float wx[8] = {wxa.x, wxa.y, wxa.z, wxa.w, wxb.x, wxb.y, wxb.z, wxb.w};
            float wy[8] = {wya.x, wya.y, wya.z, wya.w, wyb.x, wyb.y, wyb.z, wyb.w};
            float bc[8] = {bba.x, bba.y, bba.z, bba.w, bbb.x, bbb.y, bbb.z, bbb.w};
#pragma unroll
            for (int pp = 0; pp < 2; ++pp) {
                const float px = pp ? xy1.x : xy0.x;
                const float py = pp ? xy1.y : xy0.y;
                float a[8];
#pragma unroll
                for (int e = 0; e < 8; ++e)
                    a[e] = fmaf(px, wx[e], fmaf(py, wy[e], bc[e]));
                sin_split_pk(a[0], a[1], X1h[pp][c].w[0], X1l[pp][c].w[0]);
                sin_split_pk(a[2], a[3], X1h[pp][c].w[1], X1l[pp][c].w[1]);
                sin_split_pk(a[4], a[5], X1h[pp][c].w[2], X1l[pp][c].w[2]);
                sin_split_pk(a[6], a[7], X1h[pp][c].w[3], X1l[pp][c].w[3]);
            }
        }

        // ---- L2: 3-term hi/lo split; weight frags read once, used 6x
        f32x4 A2[2][8];
        initb2(A2, 0);
#pragma unroll
        for (int c = 0; c < 4; ++c)
#pragma unroll
            for (int mt = 0; mt < 8; ++mt) {
                f16x8 ah = *(const f16x8*)(L2Hp + (c * 8 + mt) * 1024 + lb);
                f16x8 al = *(const f16x8*)(W2Lp + (c * 8 + mt) * 1024 + lb);
#pragma unroll
                for (int pp = 0; pp < 2; ++pp) {
                    A2[pp][mt] = MFMA16(ah, X1h[pp][c].v, A2[pp][mt], 0, 0, 0);
                    A2[pp][mt] = MFMA16(ah, X1l[pp][c].v, A2[pp][mt], 0, 0, 0);
                    A2[pp][mt] = MFMA16(al, X1h[pp][c].v, A2[pp][mt], 0, 0, 0);
                }
            }

        UF X2h[2][4];
        epi_hi2(A2, X2h);

        // ---- L3: 1-term (X2 hi only; RTE-packed above)
        f32x4 A3[2][8];
        initb2(A3, 1);
#pragma unroll
        for (int c = 0; c < 4; ++c)
#pragma unroll
            for (int mt = 0; mt < 8; ++mt) {
                f16x8 ah = *(const f16x8*)(L3Hp + (c * 8 + mt) * 1024 + lb);
#pragma unroll
                for (int pp = 0; pp < 2; ++pp)
                    A3[pp][mt] = MFMA16(ah, X2h[pp][c].v, A3[pp][mt], 0, 0, 0);
            }

        UF X3h[2][4];
        epi_hi2(A3, X3h);

        // ---- L4: plain f16
        f32x4 A4[2][8];
        initb2(A4, 2);
#pragma unroll
        for (int c = 0; c < 4; ++c)
#pragma unroll
            for (int mt = 0; mt < 8; ++mt) {
                f16x8 ah = *(const f16x8*)(L4Hp + (c * 8 + mt) * 1024 + lb);
#pragma unroll
                for (int pp = 0; pp < 2; ++pp)
                    A4[pp][mt] = MFMA16(ah, X3h[pp][c].v, A4[pp][mt], 0, 0, 0);
            }

        UF X4h[2][4];
        epi_hi2(A4, X4h);

        // ---- L5: single M-padded tile per point-tile
        f32x4 a5[2] = {{0.f, 0.f, 0.f, 0.f}, {0.f, 0.f, 0.f, 0.f}};
#pragma unroll
        for (int c = 0; c < 4; ++c) {
            f16x8 ah = *(const f16x8*)(L5Hp + c * 1024 + lb);
#pragma unroll
            for (int pp = 0; pp < 2; ++pp)
                a5[pp] = MFMA16(ah, X4h[pp][c].v, a5[pp], 0, 0, 0);
        }

        if (g == 0) {   // rows 0..2 = outputs j=0..2 for point n
#pragma unroll
            for (int pp = 0; pp < 2; ++pp) {
                size_t o = ((size_t)b * N_ + ptb + pp * 16 + n) * 3;
                out[o]     = a5[pp][0] + b5_0;
                out[o + 1] = a5[pp][1] + b5_1;
                out[o + 2] = a5[pp][2] + b5_2;
            }
        }
    }
}

extern "C" void kernel_launch(void* const* d_in, const int* in_sizes, int n_in,
                              void* d_out, int out_size, void* d_ws, size_t ws_size,
                              hipStream_t stream) {
    (void)in_sizes; (void)n_in; (void)out_size; (void)ws_size;
    const float* x = (const float*)d_in[0];
    const float* p = (const float*)d_in[1];
    float* o = (float*)d_out;
    char* ws = (char*)d_ws;   // needs 32 * 136704 = 4,374,528 B

    (void)hipFuncSetAttribute(reinterpret_cast<const void*>(siren_main),
                              hipFuncAttributeMaxDynamicSharedMemorySize, LDSSET);
    siren_prep<<<dim3(102, 32), 64, 0, stream>>>(p, ws);
    siren_main<<<dim3(32, 8), NTHR, LDSSET, stream>>>(x, p, o, ws);
}